// Round 4
// baseline (398.087 us; speedup 1.0000x reference)
//
#include <hip/hip_runtime.h>
#include <stdint.h>

#define BB 2
#define SS 2048
#define DD 1024
#define HH 16
#define DKK 64
#define MT (BB*SS)   // 4096 rows total

using short8  = __attribute__((ext_vector_type(8))) short;   // 8 x bf16 bits (4 VGPRs)
using floatx4 = __attribute__((ext_vector_type(4))) float;
typedef unsigned short u16;

__device__ __forceinline__ float b2f(u16 x) {
  union { unsigned u; float f; } v; v.u = ((unsigned)x) << 16; return v.f;
}
__device__ __forceinline__ u16 f2b(float f) {   // RNE float->bf16
  union { float f; unsigned u; } v; v.f = f;
  return (u16)((v.u + 0x7FFFu + ((v.u >> 16) & 1u)) >> 16);
}
// pack 16 consecutive floats (4 x float4) into two short8 bf16 fragments
__device__ __forceinline__ void pack16(const float4* p, short8& lo, short8& hi) {
  float4 x0 = p[0], x1 = p[1], x2 = p[2], x3 = p[3];
  lo[0]=(short)f2b(x0.x); lo[1]=(short)f2b(x0.y); lo[2]=(short)f2b(x0.z); lo[3]=(short)f2b(x0.w);
  lo[4]=(short)f2b(x1.x); lo[5]=(short)f2b(x1.y); lo[6]=(short)f2b(x1.z); lo[7]=(short)f2b(x1.w);
  hi[0]=(short)f2b(x2.x); hi[1]=(short)f2b(x2.y); hi[2]=(short)f2b(x2.z); hi[3]=(short)f2b(x2.w);
  hi[4]=(short)f2b(x3.x); hi[5]=(short)f2b(x3.y); hi[6]=(short)f2b(x3.z); hi[7]=(short)f2b(x3.w);
}

// ---------------------------------------------------------------------------
// GEMM core: C[128x128 tile at m0,n0] = A[M,K] @ W[N,K]^T + bias[N]
// A is fp32 (A_BF16=false) or bf16 (true). W/bias always fp32 (harness inputs).
// Output: bf16 u16 (OUT_F32=false) or fp32 (true). fp32 accumulation.
// permute=1: scatter C[m,n] into [B,H,S,dk] head-split layout.
// ---------------------------------------------------------------------------
template<bool A_BF16, bool OUT_F32>
__device__ __forceinline__ void gemm_core(
    const void* __restrict__ A, const float* __restrict__ W,
    const float* __restrict__ bias, void* __restrict__ Cv,
    const int K, const int N, const int m0, const int n0, const int permute)
{
  __shared__ __align__(16) u16 sA[128*32];
  __shared__ __align__(16) u16 sB[128*32];

  const int tid  = threadIdx.x;
  const int wave = tid >> 6;
  const int lane = tid & 63;
  const int quad = lane >> 4;       // 0..3
  const int lr   = lane & 15;
  const int wm   = wave >> 1;
  const int wn   = wave & 1;
  const int srow = tid >> 1;        // staging row 0..127
  const int scol = (tid & 1) * 16;  // staging col 0 or 16 (elements)

  floatx4 acc[4][4];
#pragma unroll
  for (int i = 0; i < 4; ++i)
#pragma unroll
    for (int j = 0; j < 4; ++j) acc[i][j] = (floatx4){0.f, 0.f, 0.f, 0.f};

  const size_t offA = (size_t)(m0 + srow) * K + scol;
  const size_t offW = (size_t)(n0 + srow) * K + scol;

  const int nk = K >> 5;
  for (int kt = 0; kt < nk; ++kt) {
    const int k0 = kt << 5;
    short8 a0, a1, b0, b1;
    if (A_BF16) {
      const u16* p = (const u16*)A + offA + k0;
      a0 = *(const short8*)p; a1 = *(const short8*)(p + 8);
    } else {
      pack16((const float4*)((const float*)A + offA + k0), a0, a1);
    }
    pack16((const float4*)(W + offW + k0), b0, b1);
    __syncthreads();   // previous tile's fragment reads complete
    *(short8*)(sA + srow * 32 + scol)     = a0;
    *(short8*)(sA + srow * 32 + scol + 8) = a1;
    *(short8*)(sB + srow * 32 + scol)     = b0;
    *(short8*)(sB + srow * 32 + scol + 8) = b1;
    __syncthreads();   // staging visible

    short8 af[4], bf[4];
#pragma unroll
    for (int t = 0; t < 4; ++t) {
      af[t] = *(const short8*)(sA + (wm*64 + t*16 + lr)*32 + quad*8);
      bf[t] = *(const short8*)(sB + (wn*64 + t*16 + lr)*32 + quad*8);
    }
#pragma unroll
    for (int i = 0; i < 4; ++i)
#pragma unroll
      for (int j = 0; j < 4; ++j)
        acc[i][j] = __builtin_amdgcn_mfma_f32_16x16x32_bf16(af[i], bf[j], acc[i][j], 0, 0, 0);
  }

  // epilogue: C/D layout col (lane&15) = n, row (quad*4+reg) = m
#pragma unroll
  for (int i = 0; i < 4; ++i) {
    const int mb = m0 + wm*64 + i*16 + quad*4;
#pragma unroll
    for (int j = 0; j < 4; ++j) {
      const int n = n0 + wn*64 + j*16 + lr;
      const float bsv = bias[n];
#pragma unroll
      for (int r = 0; r < 4; ++r) {
        const int m = mb + r;
        const float v = acc[i][j][r] + bsv;
        size_t idx;
        if (permute) {
          const int bb = m >> 11, s = m & (SS - 1);
          const int hh = n >> 6,  dh = n & (DKK - 1);
          idx = (((size_t)(bb * HH + hh)) * SS + s) * DKK + dh;
        } else {
          idx = (size_t)m * N + n;
        }
        if (OUT_F32) ((float*)Cv)[idx] = v;
        else         ((u16*)Cv)[idx]   = f2b(v);
      }
    }
  }
}

__global__ __launch_bounds__(256, 2) void gemm_qkv(
    const float* __restrict__ Qin, const float* __restrict__ Kin, const float* __restrict__ Vin,
    const float* __restrict__ Wq, const float* __restrict__ Wk, const float* __restrict__ Wv,
    const float* __restrict__ bq, const float* __restrict__ bk, const float* __restrict__ bv,
    u16* __restrict__ oQ, u16* __restrict__ oK, u16* __restrict__ oV)
{
  const int wsel = blockIdx.x >> 3;          // 0:Q 1:K 2:V
  const int n0 = (blockIdx.x & 7) * 128;
  const int m0 = blockIdx.y * 128;
  const float* A; const float* W; const float* bias; u16* C;
  if (wsel == 0)      { A = Qin; W = Wq; bias = bq; C = oQ; }
  else if (wsel == 1) { A = Kin; W = Wk; bias = bk; C = oK; }
  else                { A = Vin; W = Wv; bias = bv; C = oV; }
  gemm_core<false, false>(A, W, bias, C, DD, DD, m0, n0, 1);
}

__global__ __launch_bounds__(256, 2) void gemm_out(
    const u16* __restrict__ A, const float* __restrict__ W,
    const float* __restrict__ bias, float* __restrict__ C)
{
  gemm_core<true, true>(A, W, bias, C, DD, DD, blockIdx.y * 128, blockIdx.x * 128, 0);
}

// ---------------------------------------------------------------------------
// V transpose per head: Vh[B,H,S,dk] -> Vt[B,H,dk,S]  (64x64 tiles via LDS)
// ---------------------------------------------------------------------------
__global__ __launch_bounds__(256) void transpose_v(
    const u16* __restrict__ Vh, u16* __restrict__ Vt)
{
  __shared__ u16 t[64 * 65];   // +1 pad: conflict-free column reads
  const int st = blockIdx.x, h = blockIdx.y, b = blockIdx.z;
  const size_t base = ((size_t)(b * HH + h)) * SS * DKK;

  const int r  = threadIdx.x >> 2;
  const int c0 = (threadIdx.x & 3) * 16;
  const u16* src = Vh + base + (size_t)(st * 64 + r) * DKK + c0;
  short8 v0 = *(const short8*)src;
  short8 v1 = *(const short8*)(src + 8);
#pragma unroll
  for (int i = 0; i < 8; ++i) {
    t[r * 65 + c0 + i]     = (u16)v0[i];
    t[r * 65 + c0 + 8 + i] = (u16)v1[i];
  }
  __syncthreads();
  union { u16 a[16]; short8 v[2]; } ob;
#pragma unroll
  for (int i = 0; i < 16; ++i) ob.a[i] = t[(c0 + i) * 65 + r];
  u16* dst = Vt + base + (size_t)r * SS + st * 64 + c0;
  *(short8*)dst       = ob.v[0];
  *(short8*)(dst + 8) = ob.v[1];
}

// ---------------------------------------------------------------------------
// Flash attention: one block = 64 Q rows of one (b,h). 4 waves x 16 q-rows.
// K/V tiles of 64. Online softmax; P via per-wave LDS (C-layout -> A-layout).
// All operands are internal ws tensors (bf16 by construction).
// ---------------------------------------------------------------------------
__global__ __launch_bounds__(256, 2) void attn(
    const u16* __restrict__ Qh, const u16* __restrict__ Kh,
    const u16* __restrict__ Vt, u16* __restrict__ O)
{
  __shared__ __align__(16) u16 sQ[64 * 64];
  __shared__ __align__(16) u16 sK[64 * 64];
  __shared__ __align__(16) u16 sV[64 * 64];      // [d][kk]
  __shared__ __align__(16) u16 sP[4][16 * 64];   // per-wave P tile

  const int tid = threadIdx.x, wave = tid >> 6, lane = tid & 63;
  const int quad = lane >> 4, lr = lane & 15;
  const int qb = blockIdx.x, h = blockIdx.y, b = blockIdx.z;
  const size_t head = ((size_t)(b * HH + h)) * SS * DKK;

  {  // load Q tile (rows qb*64..+63)
    const int r = tid >> 2, c = (tid & 3) * 16;
    const short8* src = (const short8*)(Qh + head + (size_t)(qb * 64 + r) * DKK + c);
    short8* dst = (short8*)(sQ + r * 64 + c);
    dst[0] = src[0]; dst[1] = src[1];
  }

  floatx4 accO[4];
  float mrow[4], lsum[4];
#pragma unroll
  for (int r = 0; r < 4; ++r) { mrow[r] = -3e38f; lsum[r] = 0.f; }
#pragma unroll
  for (int t = 0; t < 4; ++t) accO[t] = (floatx4){0.f, 0.f, 0.f, 0.f};

  for (int kt = 0; kt < SS / 64; ++kt) {
    __syncthreads();   // Q ready (iter0); prior iter's sK/sV reads done
    {
      const int r = tid >> 2, c = (tid & 3) * 16;
      const short8* sk = (const short8*)(Kh + head + (size_t)(kt * 64 + r) * DKK + c);
      short8* dk = (short8*)(sK + r * 64 + c);
      dk[0] = sk[0]; dk[1] = sk[1];
      const short8* sv = (const short8*)(Vt + head + (size_t)r * SS + kt * 64 + c);
      short8* dv = (short8*)(sV + r * 64 + c);
      dv[0] = sv[0]; dv[1] = sv[1];
    }
    __syncthreads();

    // S = Q @ K^T for this wave's 16 q-rows x 64 kk
    short8 a0 = *(const short8*)(sQ + (wave * 16 + lr) * 64 + quad * 8);
    short8 a1 = *(const short8*)(sQ + (wave * 16 + lr) * 64 + 32 + quad * 8);
    floatx4 sc[4];
#pragma unroll
    for (int t = 0; t < 4; ++t) {
      short8 b0 = *(const short8*)(sK + (t * 16 + lr) * 64 + quad * 8);
      short8 b1 = *(const short8*)(sK + (t * 16 + lr) * 64 + 32 + quad * 8);
      floatx4 cc = (floatx4){0.f, 0.f, 0.f, 0.f};
      cc = __builtin_amdgcn_mfma_f32_16x16x32_bf16(a0, b0, cc, 0, 0, 0);
      cc = __builtin_amdgcn_mfma_f32_16x16x32_bf16(a1, b1, cc, 0, 0, 0);
      sc[t] = cc;
    }

    // online softmax (row q = quad*4 + r lives in the 16 lanes sharing quad)
    float alpha[4];
#pragma unroll
    for (int r = 0; r < 4; ++r) {
      float mx = fmaxf(fmaxf(sc[0][r], sc[1][r]), fmaxf(sc[2][r], sc[3][r]));
#pragma unroll
      for (int off = 8; off; off >>= 1) mx = fmaxf(mx, __shfl_xor(mx, off, 64));
      mx *= 0.125f;                                   // 1/sqrt(64)
      const float mn = fmaxf(mrow[r], mx);
      alpha[r] = __expf(mrow[r] - mn);
      mrow[r] = mn;
      float rs = 0.f;
#pragma unroll
      for (int t = 0; t < 4; ++t) {
        const float p = __expf(sc[t][r] * 0.125f - mn);
        rs += p;
        sP[wave][(quad * 4 + r) * 64 + t * 16 + lr] = f2b(p);
      }
#pragma unroll
      for (int off = 8; off; off >>= 1) rs += __shfl_xor(rs, off, 64);
      lsum[r] = lsum[r] * alpha[r] + rs;
    }
#pragma unroll
    for (int t = 0; t < 4; ++t) {
      floatx4 o = accO[t];
      o[0] *= alpha[0]; o[1] *= alpha[1]; o[2] *= alpha[2]; o[3] *= alpha[3];
      accO[t] = o;
    }
    __syncthreads();   // sP visible (uniform barrier; also orders ds ops)

    // O += P @ V   (A = P from LDS in A-layout, B = V^T tile)
    short8 p0 = *(const short8*)(sP[wave] + lr * 64 + quad * 8);
    short8 p1 = *(const short8*)(sP[wave] + lr * 64 + 32 + quad * 8);
#pragma unroll
    for (int t = 0; t < 4; ++t) {
      short8 v0 = *(const short8*)(sV + (t * 16 + lr) * 64 + quad * 8);
      short8 v1 = *(const short8*)(sV + (t * 16 + lr) * 64 + 32 + quad * 8);
      accO[t] = __builtin_amdgcn_mfma_f32_16x16x32_bf16(p0, v0, accO[t], 0, 0, 0);
      accO[t] = __builtin_amdgcn_mfma_f32_16x16x32_bf16(p1, v1, accO[t], 0, 0, 0);
    }
  }

  // write O[b, s, h*64 + d]  (merged-head layout, ready for output proj)
#pragma unroll
  for (int t = 0; t < 4; ++t) {
#pragma unroll
    for (int r = 0; r < 4; ++r) {
      const int s = qb * 64 + wave * 16 + quad * 4 + r;
      const int d = h * 64 + t * 16 + lr;
      O[((size_t)(b * SS + s)) * DD + d] = f2b(accO[t][r] / lsum[r]);
    }
  }
}

// ---------------------------------------------------------------------------
extern "C" void kernel_launch(void* const* d_in, const int* in_sizes, int n_in,
                              void* d_out, int out_size, void* d_ws, size_t ws_size,
                              hipStream_t stream)
{
  const float* Qin = (const float*)d_in[0];
  const float* Kin = (const float*)d_in[1];
  const float* Vin = (const float*)d_in[2];
  const float* Wq  = (const float*)d_in[3];
  const float* bq  = (const float*)d_in[4];
  const float* Wk  = (const float*)d_in[5];
  const float* bk  = (const float*)d_in[6];
  const float* Wv  = (const float*)d_in[7];
  const float* bv  = (const float*)d_in[8];
  const float* Wo  = (const float*)d_in[9];
  const float* bo  = (const float*)d_in[10];
  float* out = (float*)d_out;

  const size_t TSZ = (size_t)MT * DD;   // 4M elements per tensor
  u16* wsQ  = (u16*)d_ws;               // [B,H,S,dk]  bf16
  u16* wsK  = wsQ  + TSZ;               // [B,H,S,dk]  bf16
  u16* wsV  = wsK  + TSZ;               // [B,H,S,dk]  bf16
  u16* wsVt = wsV  + TSZ;               // [B,H,dk,S]  bf16
  u16* wsO  = wsVt + TSZ;               // [B,S,D]     bf16  (40 MB total)

  dim3 blk(256);
  gemm_qkv<<<dim3(24, MT / 128), blk, 0, stream>>>(Qin, Kin, Vin, Wq, Wk, Wv,
                                                   bq, bk, bv, wsQ, wsK, wsV);
  transpose_v<<<dim3(SS / 64, HH, BB), blk, 0, stream>>>(wsV, wsVt);
  attn<<<dim3(SS / 64, HH, BB), blk, 0, stream>>>(wsQ, wsK, wsVt, wsO);
  gemm_out<<<dim3(DD / 128, MT / 128), blk, 0, stream>>>(wsO, Wo, bo, out);
}

// Round 6
// 348.996 us; speedup vs baseline: 1.1407x; 1.1407x over previous
//
#include <hip/hip_runtime.h>
#include <stdint.h>

#define BB 2
#define SS 2048
#define DD 1024
#define HH 16
#define DKK 64
#define MT (BB*SS)   // 4096 rows total

#define GSTRIDE 40   // GEMM LDS row stride (elem): 80B -> fragment reads conflict-free
#define ASTRIDE 72   // attn LDS row stride (elem): 144B -> fragment reads conflict-free

using short8  = __attribute__((ext_vector_type(8))) short;   // 8 x bf16 bits (4 VGPRs)
using floatx4 = __attribute__((ext_vector_type(4))) float;
typedef unsigned short u16;

__device__ __forceinline__ u16 f2b(float f) {   // RNE float->bf16
  union { float f; unsigned u; } v; v.f = f;
  return (u16)((v.u + 0x7FFFu + ((v.u >> 16) & 1u)) >> 16);
}
// pack 16 consecutive floats (4 x float4) into two short8 bf16 fragments
__device__ __forceinline__ void pack16(const float4* p, short8& lo, short8& hi) {
  float4 x0 = p[0], x1 = p[1], x2 = p[2], x3 = p[3];
  lo[0]=(short)f2b(x0.x); lo[1]=(short)f2b(x0.y); lo[2]=(short)f2b(x0.z); lo[3]=(short)f2b(x0.w);
  lo[4]=(short)f2b(x1.x); lo[5]=(short)f2b(x1.y); lo[6]=(short)f2b(x1.z); lo[7]=(short)f2b(x1.w);
  hi[0]=(short)f2b(x2.x); hi[1]=(short)f2b(x2.y); hi[2]=(short)f2b(x2.z); hi[3]=(short)f2b(x2.w);
  hi[4]=(short)f2b(x3.x); hi[5]=(short)f2b(x3.y); hi[6]=(short)f2b(x3.z); hi[7]=(short)f2b(x3.w);
}

// ---------------------------------------------------------------------------
// GEMM core: C[128x128 tile at m0,n0] = A[M,K] @ W[N,K]^T + bias[N]
// A bf16 or fp32 per template; W fp32; fp32 acc; C bf16 or fp32, row-major.
// LDS rows padded to GSTRIDE elems -> conflict-free ds_read_b128 fragments.
// ---------------------------------------------------------------------------
template<bool A_BF16, bool OUT_F32>
__device__ __forceinline__ void gemm_core(
    const void* __restrict__ A, const float* __restrict__ W,
    const float* __restrict__ bias, void* __restrict__ Cv,
    const int K, const int N, const int m0, const int n0)
{
  __shared__ __align__(16) u16 sA[128*GSTRIDE];
  __shared__ __align__(16) u16 sB[128*GSTRIDE];

  const int tid  = threadIdx.x;
  const int wave = tid >> 6;
  const int lane = tid & 63;
  const int quad = lane >> 4;       // 0..3
  const int lr   = lane & 15;
  const int wm   = wave >> 1;
  const int wn   = wave & 1;
  const int srow = tid >> 1;        // staging row 0..127
  const int scol = (tid & 1) * 16;  // staging col 0 or 16 (elements)

  floatx4 acc[4][4];
#pragma unroll
  for (int i = 0; i < 4; ++i)
#pragma unroll
    for (int j = 0; j < 4; ++j) acc[i][j] = (floatx4){0.f, 0.f, 0.f, 0.f};

  const size_t offA = (size_t)(m0 + srow) * K + scol;
  const size_t offW = (size_t)(n0 + srow) * K + scol;

  const int nk = K >> 5;
  for (int kt = 0; kt < nk; ++kt) {
    const int k0 = kt << 5;
    short8 a0, a1, b0, b1;
    if (A_BF16) {
      const u16* p = (const u16*)A + offA + k0;
      a0 = *(const short8*)p; a1 = *(const short8*)(p + 8);
    } else {
      pack16((const float4*)((const float*)A + offA + k0), a0, a1);
    }
    pack16((const float4*)(W + offW + k0), b0, b1);
    __syncthreads();   // previous tile's fragment reads complete
    *(short8*)(sA + srow * GSTRIDE + scol)     = a0;
    *(short8*)(sA + srow * GSTRIDE + scol + 8) = a1;
    *(short8*)(sB + srow * GSTRIDE + scol)     = b0;
    *(short8*)(sB + srow * GSTRIDE + scol + 8) = b1;
    __syncthreads();   // staging visible

    short8 af[4], bf[4];
#pragma unroll
    for (int t = 0; t < 4; ++t) {
      af[t] = *(const short8*)(sA + (wm*64 + t*16 + lr)*GSTRIDE + quad*8);
      bf[t] = *(const short8*)(sB + (wn*64 + t*16 + lr)*GSTRIDE + quad*8);
    }
#pragma unroll
    for (int i = 0; i < 4; ++i)
#pragma unroll
      for (int j = 0; j < 4; ++j)
        acc[i][j] = __builtin_amdgcn_mfma_f32_16x16x32_bf16(af[i], bf[j], acc[i][j], 0, 0, 0);
  }

  // epilogue: C/D layout col (lane&15) = n, row (quad*4+reg) = m
#pragma unroll
  for (int i = 0; i < 4; ++i) {
    const int mb = m0 + wm*64 + i*16 + quad*4;
#pragma unroll
    for (int j = 0; j < 4; ++j) {
      const int n = n0 + wn*64 + j*16 + lr;
      const float bsv = bias[n];
#pragma unroll
      for (int r = 0; r < 4; ++r) {
        const size_t idx = (size_t)(mb + r) * N + n;
        const float v = acc[i][j][r] + bsv;
        if (OUT_F32) ((float*)Cv)[idx] = v;
        else         ((u16*)Cv)[idx]   = f2b(v);
      }
    }
  }
}

__global__ __launch_bounds__(256, 2) void gemm_qkv(
    const float* __restrict__ Qin, const float* __restrict__ Kin, const float* __restrict__ Vin,
    const float* __restrict__ Wq, const float* __restrict__ Wk, const float* __restrict__ Wv,
    const float* __restrict__ bq, const float* __restrict__ bk, const float* __restrict__ bv,
    u16* __restrict__ oQ, u16* __restrict__ oK, u16* __restrict__ oV)
{
  const int wsel = blockIdx.x >> 3;          // 0:Q 1:K 2:V
  const int n0 = (blockIdx.x & 7) * 128;
  const int m0 = blockIdx.y * 128;
  const float* A; const float* W; const float* bias; u16* C;
  if (wsel == 0)      { A = Qin; W = Wq; bias = bq; C = oQ; }
  else if (wsel == 1) { A = Kin; W = Wk; bias = bk; C = oK; }
  else                { A = Vin; W = Wv; bias = bv; C = oV; }
  gemm_core<false, false>(A, W, bias, C, DD, DD, m0, n0);
}

__global__ __launch_bounds__(256, 2) void gemm_out(
    const u16* __restrict__ A, const float* __restrict__ W,
    const float* __restrict__ bias, float* __restrict__ C)
{
  gemm_core<true, true>((const void*)A, W, bias, C, DD, DD,
                        blockIdx.y * 128, blockIdx.x * 128);
}

// ---------------------------------------------------------------------------
// V transpose: pV[B,S,D] (head h cols h*64..) -> Vt[B,H,dk,S]  (64x64 tiles)
// ---------------------------------------------------------------------------
__global__ __launch_bounds__(256) void transpose_v(
    const u16* __restrict__ Vp, u16* __restrict__ Vt)
{
  __shared__ u16 t[64 * 65];   // +1 pad: conflict-free column reads
  const int st = blockIdx.x, h = blockIdx.y, b = blockIdx.z;

  const int r  = threadIdx.x >> 2;
  const int c0 = (threadIdx.x & 3) * 16;
  const u16* src = Vp + ((size_t)(b * SS + st * 64 + r)) * DD + h * 64 + c0;
  short8 v0 = *(const short8*)src;
  short8 v1 = *(const short8*)(src + 8);
#pragma unroll
  for (int i = 0; i < 8; ++i) {
    t[r * 65 + c0 + i]     = (u16)v0[i];
    t[r * 65 + c0 + 8 + i] = (u16)v1[i];
  }
  __syncthreads();
  union { u16 a[16]; short8 v[2]; } ob;
#pragma unroll
  for (int i = 0; i < 16; ++i) ob.a[i] = t[(c0 + i) * 65 + r];
  u16* dst = Vt + (((size_t)(b * HH + h)) * DKK + r) * SS + st * 64 + c0;
  *(short8*)dst       = ob.v[0];
  *(short8*)(dst + 8) = ob.v[1];
}

// ---------------------------------------------------------------------------
// Flash attention: block = 64 Q rows of one (b,h); 4 waves x 16 q-rows.
// Q/K read from [B,S,D] (head cols); Vt from [B,H,dk,S]. LDS rows padded to
// ASTRIDE elems -> conflict-free b128 fragments. Online softmax.
// ---------------------------------------------------------------------------
__global__ __launch_bounds__(256, 4) void attn(
    const u16* __restrict__ Qp, const u16* __restrict__ Kp,
    const u16* __restrict__ Vt, u16* __restrict__ O)
{
  __shared__ __align__(16) u16 sQ[64 * ASTRIDE];
  __shared__ __align__(16) u16 sK[64 * ASTRIDE];
  __shared__ __align__(16) u16 sV[64 * ASTRIDE];      // [d][kk]
  __shared__ __align__(16) u16 sP[4][16 * ASTRIDE];   // per-wave P tile

  const int tid = threadIdx.x, wave = tid >> 6, lane = tid & 63;
  const int quad = lane >> 4, lr = lane & 15;
  const int qb = blockIdx.x, h = blockIdx.y, b = blockIdx.z;
  const size_t vbase = ((size_t)(b * HH + h)) * DKK * SS;

  {  // load Q tile (rows qb*64..+63), head cols h*64..h*64+63
    const int r = tid >> 2, c = (tid & 3) * 16;
    const short8* src = (const short8*)(Qp + ((size_t)(b * SS + qb * 64 + r)) * DD + h * 64 + c);
    short8* dst = (short8*)(sQ + r * ASTRIDE + c);
    dst[0] = src[0]; dst[1] = src[1];
  }

  floatx4 accO[4];
  float mrow[4], lsum[4];
#pragma unroll
  for (int r = 0; r < 4; ++r) { mrow[r] = -3e38f; lsum[r] = 0.f; }
#pragma unroll
  for (int t = 0; t < 4; ++t) accO[t] = (floatx4){0.f, 0.f, 0.f, 0.f};

  for (int kt = 0; kt < SS / 64; ++kt) {
    __syncthreads();   // Q ready (iter0); prior iter's sK/sV reads done
    {
      const int r = tid >> 2, c = (tid & 3) * 16;
      const short8* sk = (const short8*)(Kp + ((size_t)(b * SS + kt * 64 + r)) * DD + h * 64 + c);
      short8* dk = (short8*)(sK + r * ASTRIDE + c);
      dk[0] = sk[0]; dk[1] = sk[1];
      const short8* sv = (const short8*)(Vt + vbase + (size_t)r * SS + kt * 64 + c);
      short8* dv = (short8*)(sV + r * ASTRIDE + c);
      dv[0] = sv[0]; dv[1] = sv[1];
    }
    __syncthreads();

    // S = Q @ K^T for this wave's 16 q-rows x 64 kk
    short8 a0 = *(const short8*)(sQ + (wave * 16 + lr) * ASTRIDE + quad * 8);
    short8 a1 = *(const short8*)(sQ + (wave * 16 + lr) * ASTRIDE + 32 + quad * 8);
    floatx4 sc[4];
#pragma unroll
    for (int t = 0; t < 4; ++t) {
      short8 b0 = *(const short8*)(sK + (t * 16 + lr) * ASTRIDE + quad * 8);
      short8 b1 = *(const short8*)(sK + (t * 16 + lr) * ASTRIDE + 32 + quad * 8);
      floatx4 cc = (floatx4){0.f, 0.f, 0.f, 0.f};
      cc = __builtin_amdgcn_mfma_f32_16x16x32_bf16(a0, b0, cc, 0, 0, 0);
      cc = __builtin_amdgcn_mfma_f32_16x16x32_bf16(a1, b1, cc, 0, 0, 0);
      sc[t] = cc;
    }

    // online softmax (row q = quad*4 + r lives in the 16 lanes sharing quad)
    float alpha[4];
#pragma unroll
    for (int r = 0; r < 4; ++r) {
      float mx = fmaxf(fmaxf(sc[0][r], sc[1][r]), fmaxf(sc[2][r], sc[3][r]));
#pragma unroll
      for (int off = 8; off; off >>= 1) mx = fmaxf(mx, __shfl_xor(mx, off, 64));
      mx *= 0.125f;                                   // 1/sqrt(64)
      const float mn = fmaxf(mrow[r], mx);
      alpha[r] = __expf(mrow[r] - mn);
      mrow[r] = mn;
      float rs = 0.f;
#pragma unroll
      for (int t = 0; t < 4; ++t) {
        const float p = __expf(sc[t][r] * 0.125f - mn);
        rs += p;
        sP[wave][(quad * 4 + r) * ASTRIDE + t * 16 + lr] = f2b(p);
      }
#pragma unroll
      for (int off = 8; off; off >>= 1) rs += __shfl_xor(rs, off, 64);
      lsum[r] = lsum[r] * alpha[r] + rs;
    }
#pragma unroll
    for (int t = 0; t < 4; ++t) {
      floatx4 o = accO[t];
      o[0] *= alpha[0]; o[1] *= alpha[1]; o[2] *= alpha[2]; o[3] *= alpha[3];
      accO[t] = o;
    }
    __syncthreads();   // sP visible (uniform barrier; also orders ds ops)

    // O += P @ V   (A = P from LDS in A-layout, B = V^T tile)
    short8 p0 = *(const short8*)(sP[wave] + lr * ASTRIDE + quad * 8);
    short8 p1 = *(const short8*)(sP[wave] + lr * ASTRIDE + 32 + quad * 8);
#pragma unroll
    for (int t = 0; t < 4; ++t) {
      short8 v0 = *(const short8*)(sV + (t * 16 + lr) * ASTRIDE + quad * 8);
      short8 v1 = *(const short8*)(sV + (t * 16 + lr) * ASTRIDE + 32 + quad * 8);
      accO[t] = __builtin_amdgcn_mfma_f32_16x16x32_bf16(p0, v0, accO[t], 0, 0, 0);
      accO[t] = __builtin_amdgcn_mfma_f32_16x16x32_bf16(p1, v1, accO[t], 0, 0, 0);
    }
  }

  // write O[b, s, h*64 + d]  (merged-head layout, ready for output proj)
#pragma unroll
  for (int t = 0; t < 4; ++t) {
#pragma unroll
    for (int r = 0; r < 4; ++r) {
      const int s = qb * 64 + wave * 16 + quad * 4 + r;
      const int d = h * 64 + t * 16 + lr;
      O[((size_t)(b * SS + s)) * DD + d] = f2b(accO[t][r] / lsum[r]);
    }
  }
}

// ---------------------------------------------------------------------------
extern "C" void kernel_launch(void* const* d_in, const int* in_sizes, int n_in,
                              void* d_out, int out_size, void* d_ws, size_t ws_size,
                              hipStream_t stream)
{
  const float* Qin = (const float*)d_in[0];
  const float* Kin = (const float*)d_in[1];
  const float* Vin = (const float*)d_in[2];
  const float* Wq  = (const float*)d_in[3];
  const float* bq  = (const float*)d_in[4];
  const float* Wk  = (const float*)d_in[5];
  const float* bk  = (const float*)d_in[6];
  const float* Wv  = (const float*)d_in[7];
  const float* bv  = (const float*)d_in[8];
  const float* Wo  = (const float*)d_in[9];
  const float* bo  = (const float*)d_in[10];
  float* out = (float*)d_out;

  const size_t TSZ = (size_t)MT * DD;   // 4M elements
  u16* pQ   = (u16*)d_ws;               // [B,S,D]   bf16
  u16* pK   = pQ  + TSZ;                // [B,S,D]   bf16
  u16* pV   = pK  + TSZ;                // [B,S,D]   bf16
  u16* wsVt = pV  + TSZ;                // [B,H,dk,S] bf16
  u16* wsO  = wsVt + TSZ;               // [B,S,D]   bf16   (40 MB total)

  dim3 blk(256);
  gemm_qkv<<<dim3(24, MT/128), blk, 0, stream>>>(
      Qin, Kin, Vin, Wq, Wk, Wv, bq, bk, bv, pQ, pK, pV);
  transpose_v<<<dim3(SS/64, HH, BB), blk, 0, stream>>>(pV, wsVt);
  attn<<<dim3(SS/64, HH, BB), blk, 0, stream>>>(pQ, pK, wsVt, wsO);
  gemm_out<<<dim3(DD/128, MT/128), blk, 0, stream>>>(wsO, Wo, bo, out);
}

// Round 7
// 307.262 us; speedup vs baseline: 1.2956x; 1.1358x over previous
//
#include <hip/hip_runtime.h>
#include <stdint.h>

#define BB 2
#define SS 2048
#define DD 1024
#define HH 16
#define DKK 64
#define MT (BB*SS)   // 4096 rows total

#define GSTRIDE 40   // GEMM LDS row stride (elem): 80B -> fragment reads conflict-free
#define ASTRIDE 72   // attn LDS row stride (elem): 144B -> fragment reads conflict-free

using short8  = __attribute__((ext_vector_type(8))) short;   // 8 x bf16 bits (4 VGPRs)
using floatx4 = __attribute__((ext_vector_type(4))) float;
using u16x4   = __attribute__((ext_vector_type(4))) unsigned short;
typedef unsigned short u16;

__device__ __forceinline__ u16 f2b(float f) {   // RNE float->bf16
  union { float f; unsigned u; } v; v.f = f;
  return (u16)((v.u + 0x7FFFu + ((v.u >> 16) & 1u)) >> 16);
}
// pack 16 consecutive floats (4 x float4) into two short8 bf16 fragments
__device__ __forceinline__ void pack16(const float4* p, short8& lo, short8& hi) {
  float4 x0 = p[0], x1 = p[1], x2 = p[2], x3 = p[3];
  lo[0]=(short)f2b(x0.x); lo[1]=(short)f2b(x0.y); lo[2]=(short)f2b(x0.z); lo[3]=(short)f2b(x0.w);
  lo[4]=(short)f2b(x1.x); lo[5]=(short)f2b(x1.y); lo[6]=(short)f2b(x1.z); lo[7]=(short)f2b(x1.w);
  hi[0]=(short)f2b(x2.x); hi[1]=(short)f2b(x2.y); hi[2]=(short)f2b(x2.z); hi[3]=(short)f2b(x2.w);
  hi[4]=(short)f2b(x3.x); hi[5]=(short)f2b(x3.y); hi[6]=(short)f2b(x3.z); hi[7]=(short)f2b(x3.w);
}

// ---------------------------------------------------------------------------
// Cast Wq/Wk/Wv (fp32) -> bf16, into d_out scratch (overwritten by gemm_out).
// ---------------------------------------------------------------------------
__global__ __launch_bounds__(256) void cast_w3(
    const float* __restrict__ w0, const float* __restrict__ w1,
    const float* __restrict__ w2, u16* __restrict__ o)
{
  const float* s = (blockIdx.y == 0) ? w0 : (blockIdx.y == 1) ? w1 : w2;
  u16* d = o + (size_t)blockIdx.y * (DD * DD);
  const size_t g = (size_t)blockIdx.x * 256 + threadIdx.x;   // 8-elem group
  float4 x0 = ((const float4*)s)[g*2], x1 = ((const float4*)s)[g*2+1];
  short8 lo;
  lo[0]=(short)f2b(x0.x); lo[1]=(short)f2b(x0.y); lo[2]=(short)f2b(x0.z); lo[3]=(short)f2b(x0.w);
  lo[4]=(short)f2b(x1.x); lo[5]=(short)f2b(x1.y); lo[6]=(short)f2b(x1.z); lo[7]=(short)f2b(x1.w);
  ((short8*)d)[g] = lo;
}

// ---------------------------------------------------------------------------
// GEMM core: C[128x128 tile at m0,n0] = A[M,K] @ W[N,K]^T + bias[N]
// A/W bf16 or fp32 per template; fp32 acc; C bf16 or fp32, row-major.
// LDS rows padded to GSTRIDE elems -> conflict-free ds_read_b128 fragments.
// ---------------------------------------------------------------------------
template<bool A_BF16, bool W_BF16, bool OUT_F32>
__device__ __forceinline__ void gemm_core(
    const void* __restrict__ A, const void* __restrict__ W,
    const float* __restrict__ bias, void* __restrict__ Cv,
    const int K, const int N, const int m0, const int n0)
{
  __shared__ __align__(16) u16 sA[128*GSTRIDE];
  __shared__ __align__(16) u16 sB[128*GSTRIDE];

  const int tid  = threadIdx.x;
  const int wave = tid >> 6;
  const int lane = tid & 63;
  const int quad = lane >> 4;       // 0..3
  const int lr   = lane & 15;
  const int wm   = wave >> 1;
  const int wn   = wave & 1;
  const int srow = tid >> 1;        // staging row 0..127
  const int scol = (tid & 1) * 16;  // staging col 0 or 16 (elements)

  floatx4 acc[4][4];
#pragma unroll
  for (int i = 0; i < 4; ++i)
#pragma unroll
    for (int j = 0; j < 4; ++j) acc[i][j] = (floatx4){0.f, 0.f, 0.f, 0.f};

  const size_t offA = (size_t)(m0 + srow) * K + scol;
  const size_t offW = (size_t)(n0 + srow) * K + scol;

  const int nk = K >> 5;
  for (int kt = 0; kt < nk; ++kt) {
    const int k0 = kt << 5;
    short8 a0, a1, b0, b1;
    if (A_BF16) {
      const u16* p = (const u16*)A + offA + k0;
      a0 = *(const short8*)p; a1 = *(const short8*)(p + 8);
    } else {
      pack16((const float4*)((const float*)A + offA + k0), a0, a1);
    }
    if (W_BF16) {
      const u16* p = (const u16*)W + offW + k0;
      b0 = *(const short8*)p; b1 = *(const short8*)(p + 8);
    } else {
      pack16((const float4*)((const float*)W + offW + k0), b0, b1);
    }
    __syncthreads();   // previous tile's fragment reads complete
    *(short8*)(sA + srow * GSTRIDE + scol)     = a0;
    *(short8*)(sA + srow * GSTRIDE + scol + 8) = a1;
    *(short8*)(sB + srow * GSTRIDE + scol)     = b0;
    *(short8*)(sB + srow * GSTRIDE + scol + 8) = b1;
    __syncthreads();   // staging visible

    short8 af[4], bf[4];
#pragma unroll
    for (int t = 0; t < 4; ++t) {
      af[t] = *(const short8*)(sA + (wm*64 + t*16 + lr)*GSTRIDE + quad*8);
      bf[t] = *(const short8*)(sB + (wn*64 + t*16 + lr)*GSTRIDE + quad*8);
    }
#pragma unroll
    for (int i = 0; i < 4; ++i)
#pragma unroll
      for (int j = 0; j < 4; ++j)
        acc[i][j] = __builtin_amdgcn_mfma_f32_16x16x32_bf16(af[i], bf[j], acc[i][j], 0, 0, 0);
  }

  // epilogue: C/D layout col (lane&15) = n, row (quad*4+reg) = m
#pragma unroll
  for (int i = 0; i < 4; ++i) {
    const int mb = m0 + wm*64 + i*16 + quad*4;
#pragma unroll
    for (int j = 0; j < 4; ++j) {
      const int n = n0 + wn*64 + j*16 + lr;
      const float bsv = bias[n];
#pragma unroll
      for (int r = 0; r < 4; ++r) {
        const size_t idx = (size_t)(mb + r) * N + n;
        const float v = acc[i][j][r] + bsv;
        if (OUT_F32) ((float*)Cv)[idx] = v;
        else         ((u16*)Cv)[idx]   = f2b(v);
      }
    }
  }
}

__global__ __launch_bounds__(256, 2) void gemm_qkv(
    const float* __restrict__ Qin, const float* __restrict__ Kin, const float* __restrict__ Vin,
    const u16* __restrict__ cWq, const u16* __restrict__ cWk, const u16* __restrict__ cWv,
    const float* __restrict__ bq, const float* __restrict__ bk, const float* __restrict__ bv,
    u16* __restrict__ oQ, u16* __restrict__ oK, u16* __restrict__ oV)
{
  const int wsel = blockIdx.x >> 3;          // 0:Q 1:K 2:V
  const int n0 = (blockIdx.x & 7) * 128;
  const int m0 = blockIdx.y * 128;
  const float* A; const u16* W; const float* bias; u16* C;
  if (wsel == 0)      { A = Qin; W = cWq; bias = bq; C = oQ; }
  else if (wsel == 1) { A = Kin; W = cWk; bias = bk; C = oK; }
  else                { A = Vin; W = cWv; bias = bv; C = oV; }
  gemm_core<false, true, false>(A, W, bias, C, DD, DD, m0, n0);
}

__global__ __launch_bounds__(256, 2) void gemm_out(
    const u16* __restrict__ A, const float* __restrict__ W,
    const float* __restrict__ bias, float* __restrict__ C)
{
  gemm_core<true, false, true>((const void*)A, (const void*)W, bias, C, DD, DD,
                               blockIdx.y * 128, blockIdx.x * 128);
}

// ---------------------------------------------------------------------------
// V transpose: pV[B,S,D] (head h cols h*64..) -> Vt[B,H,dk,S]  (64x64 tiles)
// ---------------------------------------------------------------------------
__global__ __launch_bounds__(256) void transpose_v(
    const u16* __restrict__ Vp, u16* __restrict__ Vt)
{
  __shared__ u16 t[64 * 65];   // +1 pad: conflict-free column reads
  const int st = blockIdx.x, h = blockIdx.y, b = blockIdx.z;

  const int r  = threadIdx.x >> 2;
  const int c0 = (threadIdx.x & 3) * 16;
  const u16* src = Vp + ((size_t)(b * SS + st * 64 + r)) * DD + h * 64 + c0;
  short8 v0 = *(const short8*)src;
  short8 v1 = *(const short8*)(src + 8);
#pragma unroll
  for (int i = 0; i < 8; ++i) {
    t[r * 65 + c0 + i]     = (u16)v0[i];
    t[r * 65 + c0 + 8 + i] = (u16)v1[i];
  }
  __syncthreads();
  union { u16 a[16]; short8 v[2]; } ob;
#pragma unroll
  for (int i = 0; i < 16; ++i) ob.a[i] = t[(c0 + i) * 65 + r];
  u16* dst = Vt + (((size_t)(b * HH + h)) * DKK + r) * SS + st * 64 + c0;
  *(short8*)dst       = ob.v[0];
  *(short8*)(dst + 8) = ob.v[1];
}

// ---------------------------------------------------------------------------
// Flash attention, transposed-S softmax: block = 64 Q rows of one (b,h);
// 4 waves x 16 q-cols. Per k-tile: S^T = K.Q^T (A=K rows, B=Q rows) puts one
// q-column (16 k-vals) per lane -> in-lane max/sum + 2 shfls (was 4-deep x4).
// P written in [q][k] A-layout via ds_write_b64; PV phase unchanged.
// ---------------------------------------------------------------------------
__global__ __launch_bounds__(256, 4) void attn(
    const u16* __restrict__ Qp, const u16* __restrict__ Kp,
    const u16* __restrict__ Vt, u16* __restrict__ O)
{
  __shared__ __align__(16) u16 sQ[64 * ASTRIDE];
  __shared__ __align__(16) u16 sK[64 * ASTRIDE];
  __shared__ __align__(16) u16 sV[64 * ASTRIDE];      // [d][kk]
  __shared__ __align__(16) u16 sP[4][16 * ASTRIDE];   // per-wave P tile [q][k]

  const int tid = threadIdx.x, wave = tid >> 6, lane = tid & 63;
  const int quad = lane >> 4, lr = lane & 15;
  const int qb = blockIdx.x, h = blockIdx.y, b = blockIdx.z;
  const size_t vbase = ((size_t)(b * HH + h)) * DKK * SS;

  {  // load Q tile (rows qb*64..+63), head cols h*64..h*64+63
    const int r = tid >> 2, c = (tid & 3) * 16;
    const short8* src = (const short8*)(Qp + ((size_t)(b * SS + qb * 64 + r)) * DD + h * 64 + c);
    short8* dst = (short8*)(sQ + r * ASTRIDE + c);
    dst[0] = src[0]; dst[1] = src[1];
  }

  floatx4 accO[4];
  float m_l = -3e38f, l_l = 0.f;     // per-lane state for q = wave*16 + lr
#pragma unroll
  for (int t = 0; t < 4; ++t) accO[t] = (floatx4){0.f, 0.f, 0.f, 0.f};

  for (int kt = 0; kt < SS / 64; ++kt) {
    __syncthreads();   // Q ready (iter0); prior iter's sK/sV reads done
    {
      const int r = tid >> 2, c = (tid & 3) * 16;
      const short8* sk = (const short8*)(Kp + ((size_t)(b * SS + kt * 64 + r)) * DD + h * 64 + c);
      short8* dk = (short8*)(sK + r * ASTRIDE + c);
      dk[0] = sk[0]; dk[1] = sk[1];
      const short8* sv = (const short8*)(Vt + vbase + (size_t)r * SS + kt * 64 + c);
      short8* dv = (short8*)(sV + r * ASTRIDE + c);
      dv[0] = sv[0]; dv[1] = sv[1];
    }
    __syncthreads();

    // S^T[k][q] for this wave's 16 q-cols: A = K-tile rows, B = Q rows
    short8 qb0 = *(const short8*)(sQ + (wave * 16 + lr) * ASTRIDE + quad * 8);
    short8 qb1 = *(const short8*)(sQ + (wave * 16 + lr) * ASTRIDE + 32 + quad * 8);
    floatx4 st[4];
#pragma unroll
    for (int t = 0; t < 4; ++t) {
      short8 ka0 = *(const short8*)(sK + (t * 16 + lr) * ASTRIDE + quad * 8);
      short8 ka1 = *(const short8*)(sK + (t * 16 + lr) * ASTRIDE + 32 + quad * 8);
      floatx4 cc = (floatx4){0.f, 0.f, 0.f, 0.f};
      cc = __builtin_amdgcn_mfma_f32_16x16x32_bf16(ka0, qb0, cc, 0, 0, 0);
      cc = __builtin_amdgcn_mfma_f32_16x16x32_bf16(ka1, qb1, cc, 0, 0, 0);
      st[t] = cc;   // st[t][r]: S^T[k = t*16+quad*4+r][q = wave*16+lr]
    }

    // online softmax, per-lane column q = wave*16 + lr
    float mx = st[0][0];
#pragma unroll
    for (int t = 0; t < 4; ++t)
#pragma unroll
      for (int r = 0; r < 4; ++r) mx = fmaxf(mx, st[t][r]);
    mx = fmaxf(mx, __shfl_xor(mx, 16, 64));
    mx = fmaxf(mx, __shfl_xor(mx, 32, 64));
    mx *= 0.125f;                                   // 1/sqrt(64)
    const float mn = fmaxf(m_l, mx);
    const float al = __expf(m_l - mn);
    m_l = mn;
    float rs = 0.f;
    u16x4 pk[4];
#pragma unroll
    for (int t = 0; t < 4; ++t)
#pragma unroll
      for (int r = 0; r < 4; ++r) {
        const float p = __expf(st[t][r] * 0.125f - mn);
        rs += p;
        pk[t][r] = f2b(p);
      }
    rs += __shfl_xor(rs, 16, 64);
    rs += __shfl_xor(rs, 32, 64);
    l_l = l_l * al + rs;

    // alpha broadcast into accO row-layout (row m = quad*4+r -> src lane m)
    float arow[4];
#pragma unroll
    for (int r = 0; r < 4; ++r) arow[r] = __shfl(al, quad * 4 + r, 64);
#pragma unroll
    for (int t = 0; t < 4; ++t) {
      floatx4 o = accO[t];
      o[0] *= arow[0]; o[1] *= arow[1]; o[2] *= arow[2]; o[3] *= arow[3];
      accO[t] = o;
    }
    // store P rows [q-local = lr][k]: reg-consecutive k -> b64 writes
#pragma unroll
    for (int t = 0; t < 4; ++t)
      *(u16x4*)(sP[wave] + lr * ASTRIDE + t * 16 + quad * 4) = pk[t];
    __syncthreads();   // sP visible

    // O += P @ V   (A = P rows, B = V^T rows)
    short8 p0 = *(const short8*)(sP[wave] + lr * ASTRIDE + quad * 8);
    short8 p1 = *(const short8*)(sP[wave] + lr * ASTRIDE + 32 + quad * 8);
#pragma unroll
    for (int t = 0; t < 4; ++t) {
      short8 v0 = *(const short8*)(sV + (t * 16 + lr) * ASTRIDE + quad * 8);
      short8 v1 = *(const short8*)(sV + (t * 16 + lr) * ASTRIDE + 32 + quad * 8);
      accO[t] = __builtin_amdgcn_mfma_f32_16x16x32_bf16(p0, v0, accO[t], 0, 0, 0);
      accO[t] = __builtin_amdgcn_mfma_f32_16x16x32_bf16(p1, v1, accO[t], 0, 0, 0);
    }
  }

  // normalize: l for row m = quad*4+r lives in lane m
  float lrow[4];
#pragma unroll
  for (int r = 0; r < 4; ++r) lrow[r] = __shfl(l_l, quad * 4 + r, 64);

  // write O[b, s, h*64 + d]  (merged-head layout, ready for output proj)
#pragma unroll
  for (int t = 0; t < 4; ++t)
#pragma unroll
    for (int r = 0; r < 4; ++r) {
      const int s = qb * 64 + wave * 16 + quad * 4 + r;
      const int d = h * 64 + t * 16 + lr;
      O[((size_t)(b * SS + s)) * DD + d] = f2b(accO[t][r] / lrow[r]);
    }
}

// ---------------------------------------------------------------------------
extern "C" void kernel_launch(void* const* d_in, const int* in_sizes, int n_in,
                              void* d_out, int out_size, void* d_ws, size_t ws_size,
                              hipStream_t stream)
{
  const float* Qin = (const float*)d_in[0];
  const float* Kin = (const float*)d_in[1];
  const float* Vin = (const float*)d_in[2];
  const float* Wq  = (const float*)d_in[3];
  const float* bq  = (const float*)d_in[4];
  const float* Wk  = (const float*)d_in[5];
  const float* bk  = (const float*)d_in[6];
  const float* Wv  = (const float*)d_in[7];
  const float* bv  = (const float*)d_in[8];
  const float* Wo  = (const float*)d_in[9];
  const float* bo  = (const float*)d_in[10];
  float* out = (float*)d_out;

  const size_t TSZ = (size_t)MT * DD;   // 4M elements
  u16* pQ   = (u16*)d_ws;               // [B,S,D]    bf16
  u16* pK   = pQ  + TSZ;                // [B,S,D]    bf16
  u16* pV   = pK  + TSZ;                // [B,S,D]    bf16
  u16* wsVt = pV  + TSZ;                // [B,H,dk,S] bf16
  u16* wsO  = wsVt + TSZ;               // [B,S,D]    bf16   (40 MB total)

  // d_out (16 MB fp32) doubles as weight-cast scratch: 3M bf16 = 6 MB used,
  // fully overwritten by gemm_out at the end (stream-ordered).
  u16* cW   = (u16*)d_out;              // cWq | cWk | cWv
  u16* cWq  = cW;
  u16* cWk  = cW + (size_t)DD * DD;
  u16* cWv  = cW + 2 * (size_t)DD * DD;

  dim3 blk(256);
  cast_w3<<<dim3(DD*DD/8/256, 3), blk, 0, stream>>>(Wq, Wk, Wv, cW);
  gemm_qkv<<<dim3(24, MT/128), blk, 0, stream>>>(
      Qin, Kin, Vin, cWq, cWk, cWv, bq, bk, bv, pQ, pK, pV);
  transpose_v<<<dim3(SS/64, HH, BB), blk, 0, stream>>>(pV, wsVt);
  attn<<<dim3(SS/64, HH, BB), blk, 0, stream>>>(pQ, pK, wsVt, wsO);
  gemm_out<<<dim3(DD/128, MT/128), blk, 0, stream>>>(wsO, Wo, bo, out);
}

// Round 8
// 273.075 us; speedup vs baseline: 1.4578x; 1.1252x over previous
//
#include <hip/hip_runtime.h>
#include <stdint.h>

#define BB 2
#define SS 2048
#define DD 1024
#define HH 16
#define DKK 64
#define MT (BB*SS)   // 4096 rows total

#define GSTRIDE 40   // fallback GEMM LDS row stride (elem): conflict-free frags
#define ASTRIDE 72   // attn LDS row stride (elem): conflict-free frags

using short8  = __attribute__((ext_vector_type(8))) short;   // 8 x bf16 bits (4 VGPRs)
using floatx4 = __attribute__((ext_vector_type(4))) float;
using u16x4   = __attribute__((ext_vector_type(4))) unsigned short;
typedef unsigned short u16;

__device__ __forceinline__ u16 f2b(float f) {   // RNE float->bf16
  union { float f; unsigned u; } v; v.f = f;
  return (u16)((v.u + 0x7FFFu + ((v.u >> 16) & 1u)) >> 16);
}
__device__ __forceinline__ void pack16(const float4* p, short8& lo, short8& hi) {
  float4 x0 = p[0], x1 = p[1], x2 = p[2], x3 = p[3];
  lo[0]=(short)f2b(x0.x); lo[1]=(short)f2b(x0.y); lo[2]=(short)f2b(x0.z); lo[3]=(short)f2b(x0.w);
  lo[4]=(short)f2b(x1.x); lo[5]=(short)f2b(x1.y); lo[6]=(short)f2b(x1.z); lo[7]=(short)f2b(x1.w);
  hi[0]=(short)f2b(x2.x); hi[1]=(short)f2b(x2.y); hi[2]=(short)f2b(x2.z); hi[3]=(short)f2b(x2.w);
  hi[4]=(short)f2b(x3.x); hi[5]=(short)f2b(x3.y); hi[6]=(short)f2b(x3.z); hi[7]=(short)f2b(x3.w);
}
// async global->LDS, 16B/lane; lds base wave-uniform, HW scatters lane i at +16*i
__device__ __forceinline__ void gload16(const u16* g, u16* l) {
  __builtin_amdgcn_global_load_lds(
      (const __attribute__((address_space(1))) void*)g,
      (__attribute__((address_space(3))) void*)l, 16, 0, 0);
}

// ---------------------------------------------------------------------------
// Casts. cast_w3: Wq/Wk/Wv -> d_out scratch (consumed by gemm_qkv before
// gemm_out overwrites d_out). cast_a3wo: Q/K/V (4M each) + Wo (1M) -> ws.
// ---------------------------------------------------------------------------
__global__ __launch_bounds__(256) void cast_w3(
    const float* __restrict__ w0, const float* __restrict__ w1,
    const float* __restrict__ w2, u16* __restrict__ o)
{
  const float* s = (blockIdx.y == 0) ? w0 : (blockIdx.y == 1) ? w1 : w2;
  u16* d = o + (size_t)blockIdx.y * (DD * DD);
  const size_t g = (size_t)blockIdx.x * 256 + threadIdx.x;   // 8-elem group
  float4 x0 = ((const float4*)s)[g*2], x1 = ((const float4*)s)[g*2+1];
  short8 lo;
  lo[0]=(short)f2b(x0.x); lo[1]=(short)f2b(x0.y); lo[2]=(short)f2b(x0.z); lo[3]=(short)f2b(x0.w);
  lo[4]=(short)f2b(x1.x); lo[5]=(short)f2b(x1.y); lo[6]=(short)f2b(x1.z); lo[7]=(short)f2b(x1.w);
  ((short8*)d)[g] = lo;
}
__global__ __launch_bounds__(256) void cast_a3wo(
    const float* __restrict__ a0, const float* __restrict__ a1,
    const float* __restrict__ a2, const float* __restrict__ a3,
    u16* __restrict__ o0, u16* __restrict__ o1,
    u16* __restrict__ o2, u16* __restrict__ o3)
{
  const int y = blockIdx.y;
  if (y == 3 && blockIdx.x >= (DD*DD/8/256)) return;   // Wo is 1M elems
  const float* s = (y == 0) ? a0 : (y == 1) ? a1 : (y == 2) ? a2 : a3;
  u16*         d = (y == 0) ? o0 : (y == 1) ? o1 : (y == 2) ? o2 : o3;
  const size_t g = (size_t)blockIdx.x * 256 + threadIdx.x;
  float4 x0 = ((const float4*)s)[g*2], x1 = ((const float4*)s)[g*2+1];
  short8 lo;
  lo[0]=(short)f2b(x0.x); lo[1]=(short)f2b(x0.y); lo[2]=(short)f2b(x0.z); lo[3]=(short)f2b(x0.w);
  lo[4]=(short)f2b(x1.x); lo[5]=(short)f2b(x1.y); lo[6]=(short)f2b(x1.z); lo[7]=(short)f2b(x1.w);
  ((short8*)d)[g] = lo;
}

// ---------------------------------------------------------------------------
// PRIMARY GEMM core (m97 structure): all-bf16, global_load_lds width-16,
// unpadded 32-elem LDS rows, 2-barrier K-loop. C = A @ W^T + bias.
// ---------------------------------------------------------------------------
template<bool OUT_F32>
__device__ __forceinline__ void gemm_async(
    const u16* __restrict__ A, const u16* __restrict__ W,
    const float* __restrict__ bias, void* __restrict__ Cv,
    const int K, const int N, const int m0, const int n0)
{
  __shared__ __align__(16) u16 sA[128*32];
  __shared__ __align__(16) u16 sB[128*32];

  const int tid  = threadIdx.x;
  const int wave = tid >> 6;
  const int lane = tid & 63;
  const int quad = lane >> 4;
  const int lr   = lane & 15;
  const int wm   = wave >> 1;
  const int wn   = wave & 1;
  const int srow = lane >> 2;        // 0..15 within 16-row chunk
  const int scol = (lane & 3) * 8;   // 0,8,16,24 elems (16B per lane)

  floatx4 acc[4][4];
#pragma unroll
  for (int i = 0; i < 4; ++i)
#pragma unroll
    for (int j = 0; j < 4; ++j) acc[i][j] = (floatx4){0.f, 0.f, 0.f, 0.f};

  // chunk c handled by this wave: c = wave and wave+4 (16 rows each)
  const u16* gA0 = A + (size_t)(m0 + wave*16       + srow) * K + scol;
  const u16* gA1 = A + (size_t)(m0 + (wave+4)*16   + srow) * K + scol;
  const u16* gW0 = W + (size_t)(n0 + wave*16       + srow) * K + scol;
  const u16* gW1 = W + (size_t)(n0 + (wave+4)*16   + srow) * K + scol;
  u16* lA0 = sA + wave*512;        // wave-uniform LDS bases (1KB chunks)
  u16* lA1 = sA + (wave+4)*512;
  u16* lB0 = sB + wave*512;
  u16* lB1 = sB + (wave+4)*512;

  const int nk = K >> 5;
  for (int kt = 0; kt < nk; ++kt) {
    const int k0 = kt << 5;
    gload16(gA0 + k0, lA0);
    gload16(gA1 + k0, lA1);
    gload16(gW0 + k0, lB0);
    gload16(gW1 + k0, lB1);
    __syncthreads();   // drains vmcnt before barrier -> staging complete

    short8 af[4], bf[4];
#pragma unroll
    for (int t = 0; t < 4; ++t) {
      af[t] = *(const short8*)(sA + (wm*64 + t*16 + lr)*32 + quad*8);
      bf[t] = *(const short8*)(sB + (wn*64 + t*16 + lr)*32 + quad*8);
    }
#pragma unroll
    for (int i = 0; i < 4; ++i)
#pragma unroll
      for (int j = 0; j < 4; ++j)
        acc[i][j] = __builtin_amdgcn_mfma_f32_16x16x32_bf16(af[i], bf[j], acc[i][j], 0, 0, 0);
    __syncthreads();   // all reads done before next iter's staging overwrites
  }

  // epilogue: C/D layout col (lane&15) = n, row (quad*4+reg) = m
#pragma unroll
  for (int i = 0; i < 4; ++i) {
    const int mb = m0 + wm*64 + i*16 + quad*4;
#pragma unroll
    for (int j = 0; j < 4; ++j) {
      const int n = n0 + wn*64 + j*16 + lr;
      const float bsv = bias[n];
#pragma unroll
      for (int r = 0; r < 4; ++r) {
        const size_t idx = (size_t)(mb + r) * N + n;
        const float v = acc[i][j][r] + bsv;
        if (OUT_F32) ((float*)Cv)[idx] = v;
        else         ((u16*)Cv)[idx]   = f2b(v);
      }
    }
  }
}

__global__ __launch_bounds__(256, 2) void gemm_qkv_async(
    const u16* __restrict__ cQ, const u16* __restrict__ cK, const u16* __restrict__ cV,
    const u16* __restrict__ cWq, const u16* __restrict__ cWk, const u16* __restrict__ cWv,
    const float* __restrict__ bq, const float* __restrict__ bk, const float* __restrict__ bv,
    u16* __restrict__ oQ, u16* __restrict__ oK, u16* __restrict__ oV)
{
  const int wsel = blockIdx.x >> 3;
  const int n0 = (blockIdx.x & 7) * 128;
  const int m0 = blockIdx.y * 128;
  const u16* A; const u16* W; const float* bias; u16* C;
  if (wsel == 0)      { A = cQ; W = cWq; bias = bq; C = oQ; }
  else if (wsel == 1) { A = cK; W = cWk; bias = bk; C = oK; }
  else                { A = cV; W = cWv; bias = bv; C = oV; }
  gemm_async<false>(A, W, bias, C, DD, DD, m0, n0);
}

__global__ __launch_bounds__(256, 2) void gemm_out_async(
    const u16* __restrict__ A, const u16* __restrict__ cWo,
    const float* __restrict__ bias, float* __restrict__ C)
{
  gemm_async<true>(A, cWo, bias, C, DD, DD, blockIdx.y * 128, blockIdx.x * 128);
}

// ---------------------------------------------------------------------------
// FALLBACK GEMM core (round-7 verified): explicit staging, padded LDS.
// ---------------------------------------------------------------------------
template<bool A_BF16, bool W_BF16, bool OUT_F32>
__device__ __forceinline__ void gemm_core(
    const void* __restrict__ A, const void* __restrict__ W,
    const float* __restrict__ bias, void* __restrict__ Cv,
    const int K, const int N, const int m0, const int n0)
{
  __shared__ __align__(16) u16 sA[128*GSTRIDE];
  __shared__ __align__(16) u16 sB[128*GSTRIDE];

  const int tid  = threadIdx.x;
  const int wave = tid >> 6;
  const int lane = tid & 63;
  const int quad = lane >> 4;
  const int lr   = lane & 15;
  const int wm   = wave >> 1;
  const int wn   = wave & 1;
  const int srow = tid >> 1;
  const int scol = (tid & 1) * 16;

  floatx4 acc[4][4];
#pragma unroll
  for (int i = 0; i < 4; ++i)
#pragma unroll
    for (int j = 0; j < 4; ++j) acc[i][j] = (floatx4){0.f, 0.f, 0.f, 0.f};

  const size_t offA = (size_t)(m0 + srow) * K + scol;
  const size_t offW = (size_t)(n0 + srow) * K + scol;

  const int nk = K >> 5;
  for (int kt = 0; kt < nk; ++kt) {
    const int k0 = kt << 5;
    short8 a0, a1, b0, b1;
    if (A_BF16) {
      const u16* p = (const u16*)A + offA + k0;
      a0 = *(const short8*)p; a1 = *(const short8*)(p + 8);
    } else {
      pack16((const float4*)((const float*)A + offA + k0), a0, a1);
    }
    if (W_BF16) {
      const u16* p = (const u16*)W + offW + k0;
      b0 = *(const short8*)p; b1 = *(const short8*)(p + 8);
    } else {
      pack16((const float4*)((const float*)W + offW + k0), b0, b1);
    }
    __syncthreads();
    *(short8*)(sA + srow * GSTRIDE + scol)     = a0;
    *(short8*)(sA + srow * GSTRIDE + scol + 8) = a1;
    *(short8*)(sB + srow * GSTRIDE + scol)     = b0;
    *(short8*)(sB + srow * GSTRIDE + scol + 8) = b1;
    __syncthreads();

    short8 af[4], bf[4];
#pragma unroll
    for (int t = 0; t < 4; ++t) {
      af[t] = *(const short8*)(sA + (wm*64 + t*16 + lr)*GSTRIDE + quad*8);
      bf[t] = *(const short8*)(sB + (wn*64 + t*16 + lr)*GSTRIDE + quad*8);
    }
#pragma unroll
    for (int i = 0; i < 4; ++i)
#pragma unroll
      for (int j = 0; j < 4; ++j)
        acc[i][j] = __builtin_amdgcn_mfma_f32_16x16x32_bf16(af[i], bf[j], acc[i][j], 0, 0, 0);
  }

#pragma unroll
  for (int i = 0; i < 4; ++i) {
    const int mb = m0 + wm*64 + i*16 + quad*4;
#pragma unroll
    for (int j = 0; j < 4; ++j) {
      const int n = n0 + wn*64 + j*16 + lr;
      const float bsv = bias[n];
#pragma unroll
      for (int r = 0; r < 4; ++r) {
        const size_t idx = (size_t)(mb + r) * N + n;
        const float v = acc[i][j][r] + bsv;
        if (OUT_F32) ((float*)Cv)[idx] = v;
        else         ((u16*)Cv)[idx]   = f2b(v);
      }
    }
  }
}

__global__ __launch_bounds__(256, 2) void gemm_qkv_fb(
    const float* __restrict__ Qin, const float* __restrict__ Kin, const float* __restrict__ Vin,
    const u16* __restrict__ cWq, const u16* __restrict__ cWk, const u16* __restrict__ cWv,
    const float* __restrict__ bq, const float* __restrict__ bk, const float* __restrict__ bv,
    u16* __restrict__ oQ, u16* __restrict__ oK, u16* __restrict__ oV)
{
  const int wsel = blockIdx.x >> 3;
  const int n0 = (blockIdx.x & 7) * 128;
  const int m0 = blockIdx.y * 128;
  const float* A; const u16* W; const float* bias; u16* C;
  if (wsel == 0)      { A = Qin; W = cWq; bias = bq; C = oQ; }
  else if (wsel == 1) { A = Kin; W = cWk; bias = bk; C = oK; }
  else                { A = Vin; W = cWv; bias = bv; C = oV; }
  gemm_core<false, true, false>(A, W, bias, C, DD, DD, m0, n0);
}
__global__ __launch_bounds__(256, 2) void gemm_out_fb(
    const u16* __restrict__ A, const float* __restrict__ W,
    const float* __restrict__ bias, float* __restrict__ C)
{
  gemm_core<true, false, true>((const void*)A, (const void*)W, bias, C, DD, DD,
                               blockIdx.y * 128, blockIdx.x * 128);
}

// ---------------------------------------------------------------------------
// V transpose: pV[B,S,D] (head h cols) -> Vt[B,H,dk,S]
// ---------------------------------------------------------------------------
__global__ __launch_bounds__(256) void transpose_v(
    const u16* __restrict__ Vp, u16* __restrict__ Vt)
{
  __shared__ u16 t[64 * 65];
  const int st = blockIdx.x, h = blockIdx.y, b = blockIdx.z;

  const int r  = threadIdx.x >> 2;
  const int c0 = (threadIdx.x & 3) * 16;
  const u16* src = Vp + ((size_t)(b * SS + st * 64 + r)) * DD + h * 64 + c0;
  short8 v0 = *(const short8*)src;
  short8 v1 = *(const short8*)(src + 8);
#pragma unroll
  for (int i = 0; i < 8; ++i) {
    t[r * 65 + c0 + i]     = (u16)v0[i];
    t[r * 65 + c0 + 8 + i] = (u16)v1[i];
  }
  __syncthreads();
  union { u16 a[16]; short8 v[2]; } ob;
#pragma unroll
  for (int i = 0; i < 16; ++i) ob.a[i] = t[(c0 + i) * 65 + r];
  u16* dst = Vt + (((size_t)(b * HH + h)) * DKK + r) * SS + st * 64 + c0;
  *(short8*)dst       = ob.v[0];
  *(short8*)(dst + 8) = ob.v[1];
}

// ---------------------------------------------------------------------------
// Flash attention (round-7 verified, transposed-S softmax). Unchanged.
// ---------------------------------------------------------------------------
__global__ __launch_bounds__(256, 4) void attn(
    const u16* __restrict__ Qp, const u16* __restrict__ Kp,
    const u16* __restrict__ Vt, u16* __restrict__ O)
{
  __shared__ __align__(16) u16 sQ[64 * ASTRIDE];
  __shared__ __align__(16) u16 sK[64 * ASTRIDE];
  __shared__ __align__(16) u16 sV[64 * ASTRIDE];
  __shared__ __align__(16) u16 sP[4][16 * ASTRIDE];

  const int tid = threadIdx.x, wave = tid >> 6, lane = tid & 63;
  const int quad = lane >> 4, lr = lane & 15;
  const int qb = blockIdx.x, h = blockIdx.y, b = blockIdx.z;
  const size_t vbase = ((size_t)(b * HH + h)) * DKK * SS;

  {
    const int r = tid >> 2, c = (tid & 3) * 16;
    const short8* src = (const short8*)(Qp + ((size_t)(b * SS + qb * 64 + r)) * DD + h * 64 + c);
    short8* dst = (short8*)(sQ + r * ASTRIDE + c);
    dst[0] = src[0]; dst[1] = src[1];
  }

  floatx4 accO[4];
  float m_l = -3e38f, l_l = 0.f;
#pragma unroll
  for (int t = 0; t < 4; ++t) accO[t] = (floatx4){0.f, 0.f, 0.f, 0.f};

  for (int kt = 0; kt < SS / 64; ++kt) {
    __syncthreads();
    {
      const int r = tid >> 2, c = (tid & 3) * 16;
      const short8* sk = (const short8*)(Kp + ((size_t)(b * SS + kt * 64 + r)) * DD + h * 64 + c);
      short8* dk = (short8*)(sK + r * ASTRIDE + c);
      dk[0] = sk[0]; dk[1] = sk[1];
      const short8* sv = (const short8*)(Vt + vbase + (size_t)r * SS + kt * 64 + c);
      short8* dv = (short8*)(sV + r * ASTRIDE + c);
      dv[0] = sv[0]; dv[1] = sv[1];
    }
    __syncthreads();

    short8 qb0 = *(const short8*)(sQ + (wave * 16 + lr) * ASTRIDE + quad * 8);
    short8 qb1 = *(const short8*)(sQ + (wave * 16 + lr) * ASTRIDE + 32 + quad * 8);
    floatx4 st[4];
#pragma unroll
    for (int t = 0; t < 4; ++t) {
      short8 ka0 = *(const short8*)(sK + (t * 16 + lr) * ASTRIDE + quad * 8);
      short8 ka1 = *(const short8*)(sK + (t * 16 + lr) * ASTRIDE + 32 + quad * 8);
      floatx4 cc = (floatx4){0.f, 0.f, 0.f, 0.f};
      cc = __builtin_amdgcn_mfma_f32_16x16x32_bf16(ka0, qb0, cc, 0, 0, 0);
      cc = __builtin_amdgcn_mfma_f32_16x16x32_bf16(ka1, qb1, cc, 0, 0, 0);
      st[t] = cc;
    }

    float mx = st[0][0];
#pragma unroll
    for (int t = 0; t < 4; ++t)
#pragma unroll
      for (int r = 0; r < 4; ++r) mx = fmaxf(mx, st[t][r]);
    mx = fmaxf(mx, __shfl_xor(mx, 16, 64));
    mx = fmaxf(mx, __shfl_xor(mx, 32, 64));
    mx *= 0.125f;
    const float mn = fmaxf(m_l, mx);
    const float al = __expf(m_l - mn);
    m_l = mn;
    float rs = 0.f;
    u16x4 pk[4];
#pragma unroll
    for (int t = 0; t < 4; ++t)
#pragma unroll
      for (int r = 0; r < 4; ++r) {
        const float p = __expf(st[t][r] * 0.125f - mn);
        rs += p;
        pk[t][r] = f2b(p);
      }
    rs += __shfl_xor(rs, 16, 64);
    rs += __shfl_xor(rs, 32, 64);
    l_l = l_l * al + rs;

    float arow[4];
#pragma unroll
    for (int r = 0; r < 4; ++r) arow[r] = __shfl(al, quad * 4 + r, 64);
#pragma unroll
    for (int t = 0; t < 4; ++t) {
      floatx4 o = accO[t];
      o[0] *= arow[0]; o[1] *= arow[1]; o[2] *= arow[2]; o[3] *= arow[3];
      accO[t] = o;
    }
#pragma unroll
    for (int t = 0; t < 4; ++t)
      *(u16x4*)(sP[wave] + lr * ASTRIDE + t * 16 + quad * 4) = pk[t];
    __syncthreads();

    short8 p0 = *(const short8*)(sP[wave] + lr * ASTRIDE + quad * 8);
    short8 p1 = *(const short8*)(sP[wave] + lr * ASTRIDE + 32 + quad * 8);
#pragma unroll
    for (int t = 0; t < 4; ++t) {
      short8 v0 = *(const short8*)(sV + (t * 16 + lr) * ASTRIDE + quad * 8);
      short8 v1 = *(const short8*)(sV + (t * 16 + lr) * ASTRIDE + 32 + quad * 8);
      accO[t] = __builtin_amdgcn_mfma_f32_16x16x32_bf16(p0, v0, accO[t], 0, 0, 0);
      accO[t] = __builtin_amdgcn_mfma_f32_16x16x32_bf16(p1, v1, accO[t], 0, 0, 0);
    }
  }

  float lrow[4];
#pragma unroll
  for (int r = 0; r < 4; ++r) lrow[r] = __shfl(l_l, quad * 4 + r, 64);

#pragma unroll
  for (int t = 0; t < 4; ++t)
#pragma unroll
    for (int r = 0; r < 4; ++r) {
      const int s = qb * 64 + wave * 16 + quad * 4 + r;
      const int d = h * 64 + t * 16 + lr;
      O[((size_t)(b * SS + s)) * DD + d] = f2b(accO[t][r] / lrow[r]);
    }
}

// ---------------------------------------------------------------------------
extern "C" void kernel_launch(void* const* d_in, const int* in_sizes, int n_in,
                              void* d_out, int out_size, void* d_ws, size_t ws_size,
                              hipStream_t stream)
{
  const float* Qin = (const float*)d_in[0];
  const float* Kin = (const float*)d_in[1];
  const float* Vin = (const float*)d_in[2];
  const float* Wq  = (const float*)d_in[3];
  const float* bq  = (const float*)d_in[4];
  const float* Wk  = (const float*)d_in[5];
  const float* bk  = (const float*)d_in[6];
  const float* Wv  = (const float*)d_in[7];
  const float* bv  = (const float*)d_in[8];
  const float* Wo  = (const float*)d_in[9];
  const float* bo  = (const float*)d_in[10];
  float* out = (float*)d_out;

  const size_t TSZ = (size_t)MT * DD;   // 4M elements
  const size_t WSZ = (size_t)DD * DD;   // 1M elements
  dim3 blk(256);

  // d_out scratch for Wq/Wk/Wv bf16 (6 MB; consumed by gemm_qkv before
  // gemm_out overwrites d_out). Verified pattern (round 7).
  u16* cWq = (u16*)d_out;
  u16* cWk = cWq + WSZ;
  u16* cWv = cWk + WSZ;

  // ws base layout (40 MB, verified): pQ pK pV wsVt wsO
  u16* pQ   = (u16*)d_ws;
  u16* pK   = pQ  + TSZ;
  u16* pV   = pK  + TSZ;
  u16* wsVt = pV  + TSZ;
  u16* wsO  = wsVt + TSZ;

  cast_w3<<<dim3(WSZ/8/256, 3), blk, 0, stream>>>(Wq, Wk, Wv, cWq);

  if (ws_size >= (8*TSZ + WSZ) * sizeof(u16)) {
    // primary: extra ws regions (no aliasing): cQ cK cV cWo
    u16* cQ  = wsO + TSZ;
    u16* cK  = cQ  + TSZ;
    u16* cV  = cK  + TSZ;
    u16* cWo = cV  + TSZ;
    cast_a3wo<<<dim3(TSZ/8/256, 4), blk, 0, stream>>>(Qin, Kin, Vin, Wo,
                                                      cQ, cK, cV, cWo);
    gemm_qkv_async<<<dim3(24, MT/128), blk, 0, stream>>>(
        cQ, cK, cV, cWq, cWk, cWv, bq, bk, bv, pQ, pK, pV);
    transpose_v<<<dim3(SS/64, HH, BB), blk, 0, stream>>>(pV, wsVt);
    attn<<<dim3(SS/64, HH, BB), blk, 0, stream>>>(pQ, pK, wsVt, wsO);
    gemm_out_async<<<dim3(DD/128, MT/128), blk, 0, stream>>>(wsO, cWo, bo, out);
  } else {
    // fallback: exact round-7 pipeline
    gemm_qkv_fb<<<dim3(24, MT/128), blk, 0, stream>>>(
        Qin, Kin, Vin, cWq, cWk, cWv, bq, bk, bv, pQ, pK, pV);
    transpose_v<<<dim3(SS/64, HH, BB), blk, 0, stream>>>(pV, wsVt);
    attn<<<dim3(SS/64, HH, BB), blk, 0, stream>>>(pQ, pK, wsVt, wsO);
    gemm_out_fb<<<dim3(DD/128, MT/128), blk, 0, stream>>>(wsO, Wo, bo, out);
  }
}

// Round 9
// 270.514 us; speedup vs baseline: 1.4716x; 1.0095x over previous
//
#include <hip/hip_runtime.h>
#include <stdint.h>

#define BB 2
#define SS 2048
#define DD 1024
#define HH 16
#define DKK 64
#define MT (BB*SS)   // 4096 rows total

#define GSTRIDE 40   // fallback GEMM LDS row stride (elem): conflict-free frags
#define ASTRIDE 72   // attn LDS row stride (elem): conflict-free frags

using short8  = __attribute__((ext_vector_type(8))) short;   // 8 x bf16 bits (4 VGPRs)
using floatx4 = __attribute__((ext_vector_type(4))) float;
using u16x4   = __attribute__((ext_vector_type(4))) unsigned short;
typedef unsigned short u16;

__device__ __forceinline__ u16 f2b(float f) {   // RNE float->bf16
  union { float f; unsigned u; } v; v.f = f;
  return (u16)((v.u + 0x7FFFu + ((v.u >> 16) & 1u)) >> 16);
}
__device__ __forceinline__ void pack16(const float4* p, short8& lo, short8& hi) {
  float4 x0 = p[0], x1 = p[1], x2 = p[2], x3 = p[3];
  lo[0]=(short)f2b(x0.x); lo[1]=(short)f2b(x0.y); lo[2]=(short)f2b(x0.z); lo[3]=(short)f2b(x0.w);
  lo[4]=(short)f2b(x1.x); lo[5]=(short)f2b(x1.y); lo[6]=(short)f2b(x1.z); lo[7]=(short)f2b(x1.w);
  hi[0]=(short)f2b(x2.x); hi[1]=(short)f2b(x2.y); hi[2]=(short)f2b(x2.z); hi[3]=(short)f2b(x2.w);
  hi[4]=(short)f2b(x3.x); hi[5]=(short)f2b(x3.y); hi[6]=(short)f2b(x3.z); hi[7]=(short)f2b(x3.w);
}
// async global->LDS, 16B/lane; lds base wave-uniform, HW scatters lane i at +16*i
__device__ __forceinline__ void gload16(const u16* g, u16* l) {
  __builtin_amdgcn_global_load_lds(
      (const __attribute__((address_space(1))) void*)g,
      (__attribute__((address_space(3))) void*)l, 16, 0, 0);
}

// ---------------------------------------------------------------------------
// Casts. cast_w3: Wq/Wk/Wv -> d_out scratch (consumed by gemm_qkv before
// gemm_out overwrites d_out). cast_a3wo: Q/K/V (4M each) + Wo (1M) -> ws.
// ---------------------------------------------------------------------------
__global__ __launch_bounds__(256) void cast_w3(
    const float* __restrict__ w0, const float* __restrict__ w1,
    const float* __restrict__ w2, u16* __restrict__ o)
{
  const float* s = (blockIdx.y == 0) ? w0 : (blockIdx.y == 1) ? w1 : w2;
  u16* d = o + (size_t)blockIdx.y * (DD * DD);
  const size_t g = (size_t)blockIdx.x * 256 + threadIdx.x;   // 8-elem group
  float4 x0 = ((const float4*)s)[g*2], x1 = ((const float4*)s)[g*2+1];
  short8 lo;
  lo[0]=(short)f2b(x0.x); lo[1]=(short)f2b(x0.y); lo[2]=(short)f2b(x0.z); lo[3]=(short)f2b(x0.w);
  lo[4]=(short)f2b(x1.x); lo[5]=(short)f2b(x1.y); lo[6]=(short)f2b(x1.z); lo[7]=(short)f2b(x1.w);
  ((short8*)d)[g] = lo;
}
__global__ __launch_bounds__(256) void cast_a3wo(
    const float* __restrict__ a0, const float* __restrict__ a1,
    const float* __restrict__ a2, const float* __restrict__ a3,
    u16* __restrict__ o0, u16* __restrict__ o1,
    u16* __restrict__ o2, u16* __restrict__ o3)
{
  const int y = blockIdx.y;
  if (y == 3 && blockIdx.x >= (DD*DD/8/256)) return;   // Wo is 1M elems
  const float* s = (y == 0) ? a0 : (y == 1) ? a1 : (y == 2) ? a2 : a3;
  u16*         d = (y == 0) ? o0 : (y == 1) ? o1 : (y == 2) ? o2 : o3;
  const size_t g = (size_t)blockIdx.x * 256 + threadIdx.x;
  float4 x0 = ((const float4*)s)[g*2], x1 = ((const float4*)s)[g*2+1];
  short8 lo;
  lo[0]=(short)f2b(x0.x); lo[1]=(short)f2b(x0.y); lo[2]=(short)f2b(x0.z); lo[3]=(short)f2b(x0.w);
  lo[4]=(short)f2b(x1.x); lo[5]=(short)f2b(x1.y); lo[6]=(short)f2b(x1.z); lo[7]=(short)f2b(x1.w);
  ((short8*)d)[g] = lo;
}

// ---------------------------------------------------------------------------
// PRIMARY GEMM core (m97 structure): all-bf16, global_load_lds width-16,
// unpadded 32-elem LDS rows, 2-barrier K-loop. C = (A @ W^T + bias) * scale.
// ---------------------------------------------------------------------------
template<bool OUT_F32>
__device__ __forceinline__ void gemm_async(
    const u16* __restrict__ A, const u16* __restrict__ W,
    const float* __restrict__ bias, void* __restrict__ Cv,
    const int K, const int N, const int m0, const int n0, const float scale)
{
  __shared__ __align__(16) u16 sA[128*32];
  __shared__ __align__(16) u16 sB[128*32];

  const int tid  = threadIdx.x;
  const int wave = tid >> 6;
  const int lane = tid & 63;
  const int quad = lane >> 4;
  const int lr   = lane & 15;
  const int wm   = wave >> 1;
  const int wn   = wave & 1;
  const int srow = lane >> 2;        // 0..15 within 16-row chunk
  const int scol = (lane & 3) * 8;   // 0,8,16,24 elems (16B per lane)

  floatx4 acc[4][4];
#pragma unroll
  for (int i = 0; i < 4; ++i)
#pragma unroll
    for (int j = 0; j < 4; ++j) acc[i][j] = (floatx4){0.f, 0.f, 0.f, 0.f};

  const u16* gA0 = A + (size_t)(m0 + wave*16       + srow) * K + scol;
  const u16* gA1 = A + (size_t)(m0 + (wave+4)*16   + srow) * K + scol;
  const u16* gW0 = W + (size_t)(n0 + wave*16       + srow) * K + scol;
  const u16* gW1 = W + (size_t)(n0 + (wave+4)*16   + srow) * K + scol;
  u16* lA0 = sA + wave*512;
  u16* lA1 = sA + (wave+4)*512;
  u16* lB0 = sB + wave*512;
  u16* lB1 = sB + (wave+4)*512;

  const int nk = K >> 5;
  for (int kt = 0; kt < nk; ++kt) {
    const int k0 = kt << 5;
    gload16(gA0 + k0, lA0);
    gload16(gA1 + k0, lA1);
    gload16(gW0 + k0, lB0);
    gload16(gW1 + k0, lB1);
    __syncthreads();

    short8 af[4], bf[4];
#pragma unroll
    for (int t = 0; t < 4; ++t) {
      af[t] = *(const short8*)(sA + (wm*64 + t*16 + lr)*32 + quad*8);
      bf[t] = *(const short8*)(sB + (wn*64 + t*16 + lr)*32 + quad*8);
    }
#pragma unroll
    for (int i = 0; i < 4; ++i)
#pragma unroll
      for (int j = 0; j < 4; ++j)
        acc[i][j] = __builtin_amdgcn_mfma_f32_16x16x32_bf16(af[i], bf[j], acc[i][j], 0, 0, 0);
    __syncthreads();
  }

  // epilogue: C/D layout col (lane&15) = n, row (quad*4+reg) = m
#pragma unroll
  for (int i = 0; i < 4; ++i) {
    const int mb = m0 + wm*64 + i*16 + quad*4;
#pragma unroll
    for (int j = 0; j < 4; ++j) {
      const int n = n0 + wn*64 + j*16 + lr;
      const float bsv = bias[n];
#pragma unroll
      for (int r = 0; r < 4; ++r) {
        const size_t idx = (size_t)(mb + r) * N + n;
        const float v = (acc[i][j][r] + bsv) * scale;
        if (OUT_F32) ((float*)Cv)[idx] = v;
        else         ((u16*)Cv)[idx]   = f2b(v);
      }
    }
  }
}

__global__ __launch_bounds__(256, 3) void gemm_qkv_async(
    const u16* __restrict__ cQ, const u16* __restrict__ cK, const u16* __restrict__ cV,
    const u16* __restrict__ cWq, const u16* __restrict__ cWk, const u16* __restrict__ cWv,
    const float* __restrict__ bq, const float* __restrict__ bk, const float* __restrict__ bv,
    u16* __restrict__ oQ, u16* __restrict__ oK, u16* __restrict__ oV)
{
  const int wsel = blockIdx.x >> 3;
  const int n0 = (blockIdx.x & 7) * 128;
  const int m0 = blockIdx.y * 128;
  const u16* A; const u16* W; const float* bias; u16* C;
  if (wsel == 0)      { A = cQ; W = cWq; bias = bq; C = oQ; }
  else if (wsel == 1) { A = cK; W = cWk; bias = bk; C = oK; }
  else                { A = cV; W = cWv; bias = bv; C = oV; }
  const float scale = (wsel == 0) ? 0.125f : 1.0f;   // Q pre-scaled by 1/sqrt(dk)
  gemm_async<false>(A, W, bias, C, DD, DD, m0, n0, scale);
}

__global__ __launch_bounds__(256, 3) void gemm_out_async(
    const u16* __restrict__ A, const u16* __restrict__ cWo,
    const float* __restrict__ bias, float* __restrict__ C)
{
  gemm_async<true>(A, cWo, bias, C, DD, DD, blockIdx.y * 128, blockIdx.x * 128, 1.0f);
}

// ---------------------------------------------------------------------------
// FALLBACK GEMM core (round-7 verified): explicit staging, padded LDS.
// ---------------------------------------------------------------------------
template<bool A_BF16, bool W_BF16, bool OUT_F32>
__device__ __forceinline__ void gemm_core(
    const void* __restrict__ A, const void* __restrict__ W,
    const float* __restrict__ bias, void* __restrict__ Cv,
    const int K, const int N, const int m0, const int n0, const float scale)
{
  __shared__ __align__(16) u16 sA[128*GSTRIDE];
  __shared__ __align__(16) u16 sB[128*GSTRIDE];

  const int tid  = threadIdx.x;
  const int wave = tid >> 6;
  const int lane = tid & 63;
  const int quad = lane >> 4;
  const int lr   = lane & 15;
  const int wm   = wave >> 1;
  const int wn   = wave & 1;
  const int srow = tid >> 1;
  const int scol = (tid & 1) * 16;

  floatx4 acc[4][4];
#pragma unroll
  for (int i = 0; i < 4; ++i)
#pragma unroll
    for (int j = 0; j < 4; ++j) acc[i][j] = (floatx4){0.f, 0.f, 0.f, 0.f};

  const size_t offA = (size_t)(m0 + srow) * K + scol;
  const size_t offW = (size_t)(n0 + srow) * K + scol;

  const int nk = K >> 5;
  for (int kt = 0; kt < nk; ++kt) {
    const int k0 = kt << 5;
    short8 a0, a1, b0, b1;
    if (A_BF16) {
      const u16* p = (const u16*)A + offA + k0;
      a0 = *(const short8*)p; a1 = *(const short8*)(p + 8);
    } else {
      pack16((const float4*)((const float*)A + offA + k0), a0, a1);
    }
    if (W_BF16) {
      const u16* p = (const u16*)W + offW + k0;
      b0 = *(const short8*)p; b1 = *(const short8*)(p + 8);
    } else {
      pack16((const float4*)((const float*)W + offW + k0), b0, b1);
    }
    __syncthreads();
    *(short8*)(sA + srow * GSTRIDE + scol)     = a0;
    *(short8*)(sA + srow * GSTRIDE + scol + 8) = a1;
    *(short8*)(sB + srow * GSTRIDE + scol)     = b0;
    *(short8*)(sB + srow * GSTRIDE + scol + 8) = b1;
    __syncthreads();

    short8 af[4], bf[4];
#pragma unroll
    for (int t = 0; t < 4; ++t) {
      af[t] = *(const short8*)(sA + (wm*64 + t*16 + lr)*GSTRIDE + quad*8);
      bf[t] = *(const short8*)(sB + (wn*64 + t*16 + lr)*GSTRIDE + quad*8);
    }
#pragma unroll
    for (int i = 0; i < 4; ++i)
#pragma unroll
      for (int j = 0; j < 4; ++j)
        acc[i][j] = __builtin_amdgcn_mfma_f32_16x16x32_bf16(af[i], bf[j], acc[i][j], 0, 0, 0);
  }

#pragma unroll
  for (int i = 0; i < 4; ++i) {
    const int mb = m0 + wm*64 + i*16 + quad*4;
#pragma unroll
    for (int j = 0; j < 4; ++j) {
      const int n = n0 + wn*64 + j*16 + lr;
      const float bsv = bias[n];
#pragma unroll
      for (int r = 0; r < 4; ++r) {
        const size_t idx = (size_t)(mb + r) * N + n;
        const float v = (acc[i][j][r] + bsv) * scale;
        if (OUT_F32) ((float*)Cv)[idx] = v;
        else         ((u16*)Cv)[idx]   = f2b(v);
      }
    }
  }
}

__global__ __launch_bounds__(256, 2) void gemm_qkv_fb(
    const float* __restrict__ Qin, const float* __restrict__ Kin, const float* __restrict__ Vin,
    const u16* __restrict__ cWq, const u16* __restrict__ cWk, const u16* __restrict__ cWv,
    const float* __restrict__ bq, const float* __restrict__ bk, const float* __restrict__ bv,
    u16* __restrict__ oQ, u16* __restrict__ oK, u16* __restrict__ oV)
{
  const int wsel = blockIdx.x >> 3;
  const int n0 = (blockIdx.x & 7) * 128;
  const int m0 = blockIdx.y * 128;
  const float* A; const u16* W; const float* bias; u16* C;
  if (wsel == 0)      { A = Qin; W = cWq; bias = bq; C = oQ; }
  else if (wsel == 1) { A = Kin; W = cWk; bias = bk; C = oK; }
  else                { A = Vin; W = cWv; bias = bv; C = oV; }
  const float scale = (wsel == 0) ? 0.125f : 1.0f;
  gemm_core<false, true, false>(A, W, bias, C, DD, DD, m0, n0, scale);
}
__global__ __launch_bounds__(256, 2) void gemm_out_fb(
    const u16* __restrict__ A, const float* __restrict__ W,
    const float* __restrict__ bias, float* __restrict__ C)
{
  gemm_core<true, false, true>((const void*)A, (const void*)W, bias, C, DD, DD,
                               blockIdx.y * 128, blockIdx.x * 128, 1.0f);
}

// ---------------------------------------------------------------------------
// V transpose: pV[B,S,D] (head h cols) -> Vt[B,H,dk,S]
// ---------------------------------------------------------------------------
__global__ __launch_bounds__(256) void transpose_v(
    const u16* __restrict__ Vp, u16* __restrict__ Vt)
{
  __shared__ u16 t[64 * 65];
  const int st = blockIdx.x, h = blockIdx.y, b = blockIdx.z;

  const int r  = threadIdx.x >> 2;
  const int c0 = (threadIdx.x & 3) * 16;
  const u16* src = Vp + ((size_t)(b * SS + st * 64 + r)) * DD + h * 64 + c0;
  short8 v0 = *(const short8*)src;
  short8 v1 = *(const short8*)(src + 8);
#pragma unroll
  for (int i = 0; i < 8; ++i) {
    t[r * 65 + c0 + i]     = (u16)v0[i];
    t[r * 65 + c0 + 8 + i] = (u16)v1[i];
  }
  __syncthreads();
  union { u16 a[16]; short8 v[2]; } ob;
#pragma unroll
  for (int i = 0; i < 16; ++i) ob.a[i] = t[(c0 + i) * 65 + r];
  u16* dst = Vt + (((size_t)(b * HH + h)) * DKK + r) * SS + st * 64 + c0;
  *(short8*)dst       = ob.v[0];
  *(short8*)(dst + 8) = ob.v[1];
}

// ---------------------------------------------------------------------------
// Flash attention (transposed-S softmax; Q pre-scaled by 1/sqrt(dk)).
// ---------------------------------------------------------------------------
__global__ __launch_bounds__(256, 4) void attn(
    const u16* __restrict__ Qp, const u16* __restrict__ Kp,
    const u16* __restrict__ Vt, u16* __restrict__ O)
{
  __shared__ __align__(16) u16 sQ[64 * ASTRIDE];
  __shared__ __align__(16) u16 sK[64 * ASTRIDE];
  __shared__ __align__(16) u16 sV[64 * ASTRIDE];
  __shared__ __align__(16) u16 sP[4][16 * ASTRIDE];

  const int tid = threadIdx.x, wave = tid >> 6, lane = tid & 63;
  const int quad = lane >> 4, lr = lane & 15;
  const int qb = blockIdx.x, h = blockIdx.y, b = blockIdx.z;
  const size_t vbase = ((size_t)(b * HH + h)) * DKK * SS;

  {
    const int r = tid >> 2, c = (tid & 3) * 16;
    const short8* src = (const short8*)(Qp + ((size_t)(b * SS + qb * 64 + r)) * DD + h * 64 + c);
    short8* dst = (short8*)(sQ + r * ASTRIDE + c);
    dst[0] = src[0]; dst[1] = src[1];
  }

  floatx4 accO[4];
  float m_l = -3e38f, l_l = 0.f;
#pragma unroll
  for (int t = 0; t < 4; ++t) accO[t] = (floatx4){0.f, 0.f, 0.f, 0.f};

  for (int kt = 0; kt < SS / 64; ++kt) {
    __syncthreads();
    {
      const int r = tid >> 2, c = (tid & 3) * 16;
      const short8* sk = (const short8*)(Kp + ((size_t)(b * SS + kt * 64 + r)) * DD + h * 64 + c);
      short8* dk = (short8*)(sK + r * ASTRIDE + c);
      dk[0] = sk[0]; dk[1] = sk[1];
      const short8* sv = (const short8*)(Vt + vbase + (size_t)r * SS + kt * 64 + c);
      short8* dv = (short8*)(sV + r * ASTRIDE + c);
      dv[0] = sv[0]; dv[1] = sv[1];
    }
    __syncthreads();

    short8 qb0 = *(const short8*)(sQ + (wave * 16 + lr) * ASTRIDE + quad * 8);
    short8 qb1 = *(const short8*)(sQ + (wave * 16 + lr) * ASTRIDE + 32 + quad * 8);
    floatx4 st[4];
#pragma unroll
    for (int t = 0; t < 4; ++t) {
      short8 ka0 = *(const short8*)(sK + (t * 16 + lr) * ASTRIDE + quad * 8);
      short8 ka1 = *(const short8*)(sK + (t * 16 + lr) * ASTRIDE + 32 + quad * 8);
      floatx4 cc = (floatx4){0.f, 0.f, 0.f, 0.f};
      cc = __builtin_amdgcn_mfma_f32_16x16x32_bf16(ka0, qb0, cc, 0, 0, 0);
      cc = __builtin_amdgcn_mfma_f32_16x16x32_bf16(ka1, qb1, cc, 0, 0, 0);
      st[t] = cc;   // already scaled scores (Q pre-scaled)
    }

    float mx = st[0][0];
#pragma unroll
    for (int t = 0; t < 4; ++t)
#pragma unroll
      for (int r = 0; r < 4; ++r) mx = fmaxf(mx, st[t][r]);
    mx = fmaxf(mx, __shfl_xor(mx, 16, 64));
    mx = fmaxf(mx, __shfl_xor(mx, 32, 64));
    const float mn = fmaxf(m_l, mx);
    const float al = __expf(m_l - mn);
    m_l = mn;
    float rs = 0.f;
    u16x4 pk[4];
#pragma unroll
    for (int t = 0; t < 4; ++t)
#pragma unroll
      for (int r = 0; r < 4; ++r) {
        const float p = __expf(st[t][r] - mn);
        rs += p;
        pk[t][r] = f2b(p);
      }
    rs += __shfl_xor(rs, 16, 64);
    rs += __shfl_xor(rs, 32, 64);
    l_l = l_l * al + rs;

    float arow[4];
#pragma unroll
    for (int r = 0; r < 4; ++r) arow[r] = __shfl(al, quad * 4 + r, 64);
#pragma unroll
    for (int t = 0; t < 4; ++t) {
      floatx4 o = accO[t];
      o[0] *= arow[0]; o[1] *= arow[1]; o[2] *= arow[2]; o[3] *= arow[3];
      accO[t] = o;
    }
#pragma unroll
    for (int t = 0; t < 4; ++t)
      *(u16x4*)(sP[wave] + lr * ASTRIDE + t * 16 + quad * 4) = pk[t];
    __syncthreads();

    short8 p0 = *(const short8*)(sP[wave] + lr * ASTRIDE + quad * 8);
    short8 p1 = *(const short8*)(sP[wave] + lr * ASTRIDE + 32 + quad * 8);
#pragma unroll
    for (int t = 0; t < 4; ++t) {
      short8 v0 = *(const short8*)(sV + (t * 16 + lr) * ASTRIDE + quad * 8);
      short8 v1 = *(const short8*)(sV + (t * 16 + lr) * ASTRIDE + 32 + quad * 8);
      accO[t] = __builtin_amdgcn_mfma_f32_16x16x32_bf16(p0, v0, accO[t], 0, 0, 0);
      accO[t] = __builtin_amdgcn_mfma_f32_16x16x32_bf16(p1, v1, accO[t], 0, 0, 0);
    }
  }

  float lrow[4];
#pragma unroll
  for (int r = 0; r < 4; ++r) lrow[r] = __shfl(l_l, quad * 4 + r, 64);

#pragma unroll
  for (int t = 0; t < 4; ++t)
#pragma unroll
    for (int r = 0; r < 4; ++r) {
      const int s = qb * 64 + wave * 16 + quad * 4 + r;
      const int d = h * 64 + t * 16 + lr;
      O[((size_t)(b * SS + s)) * DD + d] = f2b(accO[t][r] / lrow[r]);
    }
}

// ---------------------------------------------------------------------------
extern "C" void kernel_launch(void* const* d_in, const int* in_sizes, int n_in,
                              void* d_out, int out_size, void* d_ws, size_t ws_size,
                              hipStream_t stream)
{
  const float* Qin = (const float*)d_in[0];
  const float* Kin = (const float*)d_in[1];
  const float* Vin = (const float*)d_in[2];
  const float* Wq  = (const float*)d_in[3];
  const float* bq  = (const float*)d_in[4];
  const float* Wk  = (const float*)d_in[5];
  const float* bk  = (const float*)d_in[6];
  const float* Wv  = (const float*)d_in[7];
  const float* bv  = (const float*)d_in[8];
  const float* Wo  = (const float*)d_in[9];
  const float* bo  = (const float*)d_in[10];
  float* out = (float*)d_out;

  const size_t TSZ = (size_t)MT * DD;   // 4M elements
  const size_t WSZ = (size_t)DD * DD;   // 1M elements
  dim3 blk(256);

  u16* cWq = (u16*)d_out;
  u16* cWk = cWq + WSZ;
  u16* cWv = cWk + WSZ;

  u16* pQ   = (u16*)d_ws;
  u16* pK   = pQ  + TSZ;
  u16* pV   = pK  + TSZ;
  u16* wsVt = pV  + TSZ;
  u16* wsO  = wsVt + TSZ;

  cast_w3<<<dim3(WSZ/8/256, 3), blk, 0, stream>>>(Wq, Wk, Wv, cWq);

  if (ws_size >= (8*TSZ + WSZ) * sizeof(u16)) {
    u16* cQ  = wsO + TSZ;
    u16* cK  = cQ  + TSZ;
    u16* cV  = cK  + TSZ;
    u16* cWo = cV  + TSZ;
    cast_a3wo<<<dim3(TSZ/8/256, 4), blk, 0, stream>>>(Qin, Kin, Vin, Wo,
                                                      cQ, cK, cV, cWo);
    gemm_qkv_async<<<dim3(24, MT/128), blk, 0, stream>>>(
        cQ, cK, cV, cWq, cWk, cWv, bq, bk, bv, pQ, pK, pV);
    transpose_v<<<dim3(SS/64, HH, BB), blk, 0, stream>>>(pV, wsVt);
    attn<<<dim3(SS/64, HH, BB), blk, 0, stream>>>(pQ, pK, wsVt, wsO);
    gemm_out_async<<<dim3(DD/128, MT/128), blk, 0, stream>>>(wsO, cWo, bo, out);
  } else {
    gemm_qkv_fb<<<dim3(24, MT/128), blk, 0, stream>>>(
        Qin, Kin, Vin, cWq, cWk, cWv, bq, bk, bv, pQ, pK, pV);
    transpose_v<<<dim3(SS/64, HH, BB), blk, 0, stream>>>(pV, wsVt);
    attn<<<dim3(SS/64, HH, BB), blk, 0, stream>>>(pQ, pK, wsVt, wsO);
    gemm_out_fb<<<dim3(DD/128, MT/128), blk, 0, stream>>>(wsO, Wo, bo, out);
  }
}

// Round 10
// 265.711 us; speedup vs baseline: 1.4982x; 1.0181x over previous
//
#include <hip/hip_runtime.h>
#include <stdint.h>

#define BB 2
#define SS 2048
#define DD 1024
#define HH 16
#define DKK 64
#define MT (BB*SS)   // 4096 rows total

#define GSTRIDE 40   // fallback GEMM LDS row stride (elem): conflict-free frags
#define ASTRIDE 72   // attn LDS row stride (elem): conflict-free frags

using short8  = __attribute__((ext_vector_type(8))) short;   // 8 x bf16 bits (4 VGPRs)
using floatx4 = __attribute__((ext_vector_type(4))) float;
using u16x4   = __attribute__((ext_vector_type(4))) unsigned short;
typedef unsigned short u16;

__device__ __forceinline__ u16 f2b(float f) {   // RNE float->bf16
  union { float f; unsigned u; } v; v.f = f;
  return (u16)((v.u + 0x7FFFu + ((v.u >> 16) & 1u)) >> 16);
}
__device__ __forceinline__ void pack16(const float4* p, short8& lo, short8& hi) {
  float4 x0 = p[0], x1 = p[1], x2 = p[2], x3 = p[3];
  lo[0]=(short)f2b(x0.x); lo[1]=(short)f2b(x0.y); lo[2]=(short)f2b(x0.z); lo[3]=(short)f2b(x0.w);
  lo[4]=(short)f2b(x1.x); lo[5]=(short)f2b(x1.y); lo[6]=(short)f2b(x1.z); lo[7]=(short)f2b(x1.w);
  hi[0]=(short)f2b(x2.x); hi[1]=(short)f2b(x2.y); hi[2]=(short)f2b(x2.z); hi[3]=(short)f2b(x2.w);
  hi[4]=(short)f2b(x3.x); hi[5]=(short)f2b(x3.y); hi[6]=(short)f2b(x3.z); hi[7]=(short)f2b(x3.w);
}
// async global->LDS, 16B/lane; lds base wave-uniform, HW scatters lane i at +16*i
__device__ __forceinline__ void gload16(const u16* g, u16* l) {
  __builtin_amdgcn_global_load_lds(
      (const __attribute__((address_space(1))) void*)g,
      (__attribute__((address_space(3))) void*)l, 16, 0, 0);
}

// ---------------------------------------------------------------------------
// One merged cast launch: Q/K/V (2048 blk each) + Wq/Wk/Wv/Wo (512 blk each).
// ---------------------------------------------------------------------------
__global__ __launch_bounds__(256) void cast_all(
    const float* __restrict__ Qin, const float* __restrict__ Kin,
    const float* __restrict__ Vin, const float* __restrict__ Wq,
    const float* __restrict__ Wk,  const float* __restrict__ Wv,
    const float* __restrict__ Wo,
    u16* __restrict__ cQ, u16* __restrict__ cK, u16* __restrict__ cV,
    u16* __restrict__ cWq, u16* __restrict__ cWk, u16* __restrict__ cWv,
    u16* __restrict__ cWo)
{
  const int y = blockIdx.y;
  if (y >= 3 && blockIdx.x >= (DD*DD/8/256)) return;   // weights are 1M elems
  const float* s; u16* d;
  switch (y) {
    case 0: s = Qin; d = cQ;  break;
    case 1: s = Kin; d = cK;  break;
    case 2: s = Vin; d = cV;  break;
    case 3: s = Wq;  d = cWq; break;
    case 4: s = Wk;  d = cWk; break;
    case 5: s = Wv;  d = cWv; break;
    default: s = Wo; d = cWo; break;
  }
  const size_t g = (size_t)blockIdx.x * 256 + threadIdx.x;
  float4 x0 = ((const float4*)s)[g*2], x1 = ((const float4*)s)[g*2+1];
  short8 lo;
  lo[0]=(short)f2b(x0.x); lo[1]=(short)f2b(x0.y); lo[2]=(short)f2b(x0.z); lo[3]=(short)f2b(x0.w);
  lo[4]=(short)f2b(x1.x); lo[5]=(short)f2b(x1.y); lo[6]=(short)f2b(x1.z); lo[7]=(short)f2b(x1.w);
  ((short8*)d)[g] = lo;
}
__global__ __launch_bounds__(256) void cast_w3(
    const float* __restrict__ w0, const float* __restrict__ w1,
    const float* __restrict__ w2, u16* __restrict__ o)
{
  const float* s = (blockIdx.y == 0) ? w0 : (blockIdx.y == 1) ? w1 : w2;
  u16* d = o + (size_t)blockIdx.y * (DD * DD);
  const size_t g = (size_t)blockIdx.x * 256 + threadIdx.x;
  float4 x0 = ((const float4*)s)[g*2], x1 = ((const float4*)s)[g*2+1];
  short8 lo;
  lo[0]=(short)f2b(x0.x); lo[1]=(short)f2b(x0.y); lo[2]=(short)f2b(x0.z); lo[3]=(short)f2b(x0.w);
  lo[4]=(short)f2b(x1.x); lo[5]=(short)f2b(x1.y); lo[6]=(short)f2b(x1.z); lo[7]=(short)f2b(x1.w);
  ((short8*)d)[g] = lo;
}

// ---------------------------------------------------------------------------
// PRIMARY GEMM (BK=64): all-bf16, global_load_lds width-16, 2-barrier K-loop
// with HALF the barriers of BK=32. LDS rows 64 elem (128B); odd rows store
// their two 32-col halves SWAPPED (swizzle applied at the GLOBAL address so
// the linear lane->lds scatter of global_load_lds is preserved). Fragment
// readers XOR the half-select with row parity -> start banks alternate
// 4q / 16+4q across lr parity = conflict-optimal (8 phases / b128 wave read).
// ---------------------------------------------------------------------------
template<bool OUT_F32>
__device__ __forceinline__ void gemm_async(
    const u16* __restrict__ A, const u16* __restrict__ W,
    const float* __restrict__ bias, void* __restrict__ Cv,
    const int K, const int N, const int m0, const int n0, const float scale)
{
  __shared__ __align__(16) u16 sA[128*64];
  __shared__ __align__(16) u16 sB[128*64];

  const int tid  = threadIdx.x;
  const int wave = tid >> 6;
  const int lane = tid & 63;
  const int quad = lane >> 4;
  const int lr   = lane & 15;
  const int wm   = wave >> 1;
  const int wn   = wave & 1;
  const int srow = lane >> 3;                              // 0..7 within chunk
  const int swz  = (((lane & 7) ^ ((srow & 1) << 2)) << 3); // swizzled col (elems)

  floatx4 acc[4][4];
#pragma unroll
  for (int i = 0; i < 4; ++i)
#pragma unroll
    for (int j = 0; j < 4; ++j) acc[i][j] = (floatx4){0.f, 0.f, 0.f, 0.f};

  // chunk = 8 rows x 64 cols = 1KB; wave w stages chunks w, w+4, w+8, w+12
  const u16* pA[4]; const u16* pW[4];
#pragma unroll
  for (int c = 0; c < 4; ++c) {
    const int row = (wave + c*4) * 8 + srow;
    pA[c] = A + (size_t)(m0 + row) * K + swz;
    pW[c] = W + (size_t)(n0 + row) * K + swz;
  }

  const int nk = K >> 6;
  for (int kt = 0; kt < nk; ++kt) {
    const int k0 = kt << 6;
#pragma unroll
    for (int c = 0; c < 4; ++c) {
      gload16(pA[c] + k0, sA + (wave + c*4) * 512);
      gload16(pW[c] + k0, sB + (wave + c*4) * 512);
    }
    __syncthreads();   // drains vmcnt -> staging complete

#pragma unroll
    for (int h2 = 0; h2 < 2; ++h2) {     // two k-halves of the 64-wide tile
      const int csel = (quad << 3) + ((h2 ^ (lr & 1)) << 5);
      short8 af[4], bf[4];
#pragma unroll
      for (int t = 0; t < 4; ++t) {
        af[t] = *(const short8*)(sA + (wm*64 + t*16 + lr)*64 + csel);
        bf[t] = *(const short8*)(sB + (wn*64 + t*16 + lr)*64 + csel);
      }
#pragma unroll
      for (int i = 0; i < 4; ++i)
#pragma unroll
        for (int j = 0; j < 4; ++j)
          acc[i][j] = __builtin_amdgcn_mfma_f32_16x16x32_bf16(af[i], bf[j], acc[i][j], 0, 0, 0);
    }
    __syncthreads();   // reads done before next staging overwrites
  }

  // epilogue: C/D layout col (lane&15) = n, row (quad*4+reg) = m
#pragma unroll
  for (int i = 0; i < 4; ++i) {
    const int mb = m0 + wm*64 + i*16 + quad*4;
#pragma unroll
    for (int j = 0; j < 4; ++j) {
      const int n = n0 + wn*64 + j*16 + lr;
      const float bsv = bias[n];
#pragma unroll
      for (int r = 0; r < 4; ++r) {
        const size_t idx = (size_t)(mb + r) * N + n;
        const float v = (acc[i][j][r] + bsv) * scale;
        if (OUT_F32) ((float*)Cv)[idx] = v;
        else         ((u16*)Cv)[idx]   = f2b(v);
      }
    }
  }
}

__global__ __launch_bounds__(256, 3) void gemm_qkv_async(
    const u16* __restrict__ cQ, const u16* __restrict__ cK, const u16* __restrict__ cV,
    const u16* __restrict__ cWq, const u16* __restrict__ cWk, const u16* __restrict__ cWv,
    const float* __restrict__ bq, const float* __restrict__ bk, const float* __restrict__ bv,
    u16* __restrict__ oQ, u16* __restrict__ oK, u16* __restrict__ oV)
{
  const int wsel = blockIdx.x >> 3;
  const int n0 = (blockIdx.x & 7) * 128;
  const int m0 = blockIdx.y * 128;
  const u16* A; const u16* W; const float* bias; u16* C;
  if (wsel == 0)      { A = cQ; W = cWq; bias = bq; C = oQ; }
  else if (wsel == 1) { A = cK; W = cWk; bias = bk; C = oK; }
  else                { A = cV; W = cWv; bias = bv; C = oV; }
  const float scale = (wsel == 0) ? 0.125f : 1.0f;   // Q pre-scaled by 1/sqrt(dk)
  gemm_async<false>(A, W, bias, C, DD, DD, m0, n0, scale);
}

__global__ __launch_bounds__(256, 3) void gemm_out_async(
    const u16* __restrict__ A, const u16* __restrict__ cWo,
    const float* __restrict__ bias, float* __restrict__ C)
{
  gemm_async<true>(A, cWo, bias, C, DD, DD, blockIdx.y * 128, blockIdx.x * 128, 1.0f);
}

// ---------------------------------------------------------------------------
// FALLBACK GEMM core (round-7 verified): explicit staging, padded LDS.
// ---------------------------------------------------------------------------
template<bool A_BF16, bool W_BF16, bool OUT_F32>
__device__ __forceinline__ void gemm_core(
    const void* __restrict__ A, const void* __restrict__ W,
    const float* __restrict__ bias, void* __restrict__ Cv,
    const int K, const int N, const int m0, const int n0, const float scale)
{
  __shared__ __align__(16) u16 sA[128*GSTRIDE];
  __shared__ __align__(16) u16 sB[128*GSTRIDE];

  const int tid  = threadIdx.x;
  const int wave = tid >> 6;
  const int lane = tid & 63;
  const int quad = lane >> 4;
  const int lr   = lane & 15;
  const int wm   = wave >> 1;
  const int wn   = wave & 1;
  const int srow = tid >> 1;
  const int scol = (tid & 1) * 16;

  floatx4 acc[4][4];
#pragma unroll
  for (int i = 0; i < 4; ++i)
#pragma unroll
    for (int j = 0; j < 4; ++j) acc[i][j] = (floatx4){0.f, 0.f, 0.f, 0.f};

  const size_t offA = (size_t)(m0 + srow) * K + scol;
  const size_t offW = (size_t)(n0 + srow) * K + scol;

  const int nk = K >> 5;
  for (int kt = 0; kt < nk; ++kt) {
    const int k0 = kt << 5;
    short8 a0, a1, b0, b1;
    if (A_BF16) {
      const u16* p = (const u16*)A + offA + k0;
      a0 = *(const short8*)p; a1 = *(const short8*)(p + 8);
    } else {
      pack16((const float4*)((const float*)A + offA + k0), a0, a1);
    }
    if (W_BF16) {
      const u16* p = (const u16*)W + offW + k0;
      b0 = *(const short8*)p; b1 = *(const short8*)(p + 8);
    } else {
      pack16((const float4*)((const float*)W + offW + k0), b0, b1);
    }
    __syncthreads();
    *(short8*)(sA + srow * GSTRIDE + scol)     = a0;
    *(short8*)(sA + srow * GSTRIDE + scol + 8) = a1;
    *(short8*)(sB + srow * GSTRIDE + scol)     = b0;
    *(short8*)(sB + srow * GSTRIDE + scol + 8) = b1;
    __syncthreads();

    short8 af[4], bf[4];
#pragma unroll
    for (int t = 0; t < 4; ++t) {
      af[t] = *(const short8*)(sA + (wm*64 + t*16 + lr)*GSTRIDE + quad*8);
      bf[t] = *(const short8*)(sB + (wn*64 + t*16 + lr)*GSTRIDE + quad*8);
    }
#pragma unroll
    for (int i = 0; i < 4; ++i)
#pragma unroll
      for (int j = 0; j < 4; ++j)
        acc[i][j] = __builtin_amdgcn_mfma_f32_16x16x32_bf16(af[i], bf[j], acc[i][j], 0, 0, 0);
  }

#pragma unroll
  for (int i = 0; i < 4; ++i) {
    const int mb = m0 + wm*64 + i*16 + quad*4;
#pragma unroll
    for (int j = 0; j < 4; ++j) {
      const int n = n0 + wn*64 + j*16 + lr;
      const float bsv = bias[n];
#pragma unroll
      for (int r = 0; r < 4; ++r) {
        const size_t idx = (size_t)(mb + r) * N + n;
        const float v = (acc[i][j][r] + bsv) * scale;
        if (OUT_F32) ((float*)Cv)[idx] = v;
        else         ((u16*)Cv)[idx]   = f2b(v);
      }
    }
  }
}

__global__ __launch_bounds__(256, 2) void gemm_qkv_fb(
    const float* __restrict__ Qin, const float* __restrict__ Kin, const float* __restrict__ Vin,
    const u16* __restrict__ cWq, const u16* __restrict__ cWk, const u16* __restrict__ cWv,
    const float* __restrict__ bq, const float* __restrict__ bk, const float* __restrict__ bv,
    u16* __restrict__ oQ, u16* __restrict__ oK, u16* __restrict__ oV)
{
  const int wsel = blockIdx.x >> 3;
  const int n0 = (blockIdx.x & 7) * 128;
  const int m0 = blockIdx.y * 128;
  const float* A; const u16* W; const float* bias; u16* C;
  if (wsel == 0)      { A = Qin; W = cWq; bias = bq; C = oQ; }
  else if (wsel == 1) { A = Kin; W = cWk; bias = bk; C = oK; }
  else                { A = Vin; W = cWv; bias = bv; C = oV; }
  const float scale = (wsel == 0) ? 0.125f : 1.0f;
  gemm_core<false, true, false>(A, W, bias, C, DD, DD, m0, n0, scale);
}
__global__ __launch_bounds__(256, 2) void gemm_out_fb(
    const u16* __restrict__ A, const float* __restrict__ W,
    const float* __restrict__ bias, float* __restrict__ C)
{
  gemm_core<true, false, true>((const void*)A, (const void*)W, bias, C, DD, DD,
                               blockIdx.y * 128, blockIdx.x * 128, 1.0f);
}

// ---------------------------------------------------------------------------
// V transpose: pV[B,S,D] (head h cols) -> Vt[B,H,dk,S]
// ---------------------------------------------------------------------------
__global__ __launch_bounds__(256) void transpose_v(
    const u16* __restrict__ Vp, u16* __restrict__ Vt)
{
  __shared__ u16 t[64 * 65];
  const int st = blockIdx.x, h = blockIdx.y, b = blockIdx.z;

  const int r  = threadIdx.x >> 2;
  const int c0 = (threadIdx.x & 3) * 16;
  const u16* src = Vp + ((size_t)(b * SS + st * 64 + r)) * DD + h * 64 + c0;
  short8 v0 = *(const short8*)src;
  short8 v1 = *(const short8*)(src + 8);
#pragma unroll
  for (int i = 0; i < 8; ++i) {
    t[r * 65 + c0 + i]     = (u16)v0[i];
    t[r * 65 + c0 + 8 + i] = (u16)v1[i];
  }
  __syncthreads();
  union { u16 a[16]; short8 v[2]; } ob;
#pragma unroll
  for (int i = 0; i < 16; ++i) ob.a[i] = t[(c0 + i) * 65 + r];
  u16* dst = Vt + (((size_t)(b * HH + h)) * DKK + r) * SS + st * 64 + c0;
  *(short8*)dst       = ob.v[0];
  *(short8*)(dst + 8) = ob.v[1];
}

// ---------------------------------------------------------------------------
// Flash attention, q-tile 128: block = 128 Q rows of one (b,h); each wave
// handles 2 groups of 16 q-cols (transposed-S softmax, Q pre-scaled).
// Staging + barriers per q halved vs q-tile 64; the two groups' softmax
// chains are independent (ILP on the serial exp/shfl path).
// ---------------------------------------------------------------------------
__global__ __launch_bounds__(256, 2) void attn(
    const u16* __restrict__ Qp, const u16* __restrict__ Kp,
    const u16* __restrict__ Vt, u16* __restrict__ O)
{
  __shared__ __align__(16) u16 sQ[128 * ASTRIDE];
  __shared__ __align__(16) u16 sK[64 * ASTRIDE];
  __shared__ __align__(16) u16 sV[64 * ASTRIDE];
  __shared__ __align__(16) u16 sP[4][32 * ASTRIDE];   // per wave: 2 groups x 16 rows

  const int tid = threadIdx.x, wave = tid >> 6, lane = tid & 63;
  const int quad = lane >> 4, lr = lane & 15;
  const int qb = blockIdx.x, h = blockIdx.y, b = blockIdx.z;
  const size_t vbase = ((size_t)(b * HH + h)) * DKK * SS;

  {  // load Q tile: 128 rows x 64 cols
    const int r = tid >> 1, c0 = (tid & 1) * 32;
    const short8* src = (const short8*)(Qp + ((size_t)(b * SS + qb * 128 + r)) * DD + h * 64 + c0);
    short8* dst = (short8*)(sQ + r * ASTRIDE + c0);
    dst[0] = src[0]; dst[1] = src[1]; dst[2] = src[2]; dst[3] = src[3];
  }

  floatx4 accO[2][4];
  float m_l[2] = { -3e38f, -3e38f }, l_l[2] = { 0.f, 0.f };
#pragma unroll
  for (int g = 0; g < 2; ++g)
#pragma unroll
    for (int t = 0; t < 4; ++t) accO[g][t] = (floatx4){0.f, 0.f, 0.f, 0.f};

  for (int kt = 0; kt < SS / 64; ++kt) {
    __syncthreads();   // Q ready (iter0); prior iter's sK/sV/sP reads done
    {
      const int r = tid >> 2, c = (tid & 3) * 16;
      const short8* sk = (const short8*)(Kp + ((size_t)(b * SS + kt * 64 + r)) * DD + h * 64 + c);
      short8* dk = (short8*)(sK + r * ASTRIDE + c);
      dk[0] = sk[0]; dk[1] = sk[1];
      const short8* sv = (const short8*)(Vt + vbase + (size_t)r * SS + kt * 64 + c);
      short8* dv = (short8*)(sV + r * ASTRIDE + c);
      dv[0] = sv[0]; dv[1] = sv[1];
    }
    __syncthreads();

#pragma unroll
    for (int g = 0; g < 2; ++g) {
      // S^T[k][q] for this wave+group's 16 q-cols: A = K rows, B = Q rows
      short8 qv0 = *(const short8*)(sQ + (g*64 + wave*16 + lr) * ASTRIDE + quad * 8);
      short8 qv1 = *(const short8*)(sQ + (g*64 + wave*16 + lr) * ASTRIDE + 32 + quad * 8);
      floatx4 st[4];
#pragma unroll
      for (int t = 0; t < 4; ++t) {
        short8 ka0 = *(const short8*)(sK + (t*16 + lr) * ASTRIDE + quad * 8);
        short8 ka1 = *(const short8*)(sK + (t*16 + lr) * ASTRIDE + 32 + quad * 8);
        floatx4 cc = (floatx4){0.f, 0.f, 0.f, 0.f};
        cc = __builtin_amdgcn_mfma_f32_16x16x32_bf16(ka0, qv0, cc, 0, 0, 0);
        cc = __builtin_amdgcn_mfma_f32_16x16x32_bf16(ka1, qv1, cc, 0, 0, 0);
        st[t] = cc;
      }

      float mx = st[0][0];
#pragma unroll
      for (int t = 0; t < 4; ++t)
#pragma unroll
        for (int r = 0; r < 4; ++r) mx = fmaxf(mx, st[t][r]);
      mx = fmaxf(mx, __shfl_xor(mx, 16, 64));
      mx = fmaxf(mx, __shfl_xor(mx, 32, 64));
      const float mn = fmaxf(m_l[g], mx);
      const float al = __expf(m_l[g] - mn);
      m_l[g] = mn;
      float rs = 0.f;
      u16x4 pk[4];
#pragma unroll
      for (int t = 0; t < 4; ++t)
#pragma unroll
        for (int r = 0; r < 4; ++r) {
          const float p = __expf(st[t][r] - mn);
          rs += p;
          pk[t][r] = f2b(p);
        }
      rs += __shfl_xor(rs, 16, 64);
      rs += __shfl_xor(rs, 32, 64);
      l_l[g] = l_l[g] * al + rs;

      float arow[4];
#pragma unroll
      for (int r = 0; r < 4; ++r) arow[r] = __shfl(al, quad * 4 + r, 64);
#pragma unroll
      for (int t = 0; t < 4; ++t) {
        floatx4 o = accO[g][t];
        o[0] *= arow[0]; o[1] *= arow[1]; o[2] *= arow[2]; o[3] *= arow[3];
        accO[g][t] = o;
      }
#pragma unroll
      for (int t = 0; t < 4; ++t)
        *(u16x4*)(sP[wave] + (g*16 + lr) * ASTRIDE + t * 16 + quad * 4) = pk[t];
    }
    __syncthreads();   // sP visible

    // O += P @ V for both groups (V frags shared)
    short8 p00 = *(const short8*)(sP[wave] + lr * ASTRIDE + quad * 8);
    short8 p01 = *(const short8*)(sP[wave] + lr * ASTRIDE + 32 + quad * 8);
    short8 p10 = *(const short8*)(sP[wave] + (16 + lr) * ASTRIDE + quad * 8);
    short8 p11 = *(const short8*)(sP[wave] + (16 + lr) * ASTRIDE + 32 + quad * 8);
#pragma unroll
    for (int t = 0; t < 4; ++t) {
      short8 v0 = *(const short8*)(sV + (t*16 + lr) * ASTRIDE + quad * 8);
      short8 v1 = *(const short8*)(sV + (t*16 + lr) * ASTRIDE + 32 + quad * 8);
      accO[0][t] = __builtin_amdgcn_mfma_f32_16x16x32_bf16(p00, v0, accO[0][t], 0, 0, 0);
      accO[0][t] = __builtin_amdgcn_mfma_f32_16x16x32_bf16(p01, v1, accO[0][t], 0, 0, 0);
      accO[1][t] = __builtin_amdgcn_mfma_f32_16x16x32_bf16(p10, v0, accO[1][t], 0, 0, 0);
      accO[1][t] = __builtin_amdgcn_mfma_f32_16x16x32_bf16(p11, v1, accO[1][t], 0, 0, 0);
    }
  }

#pragma unroll
  for (int g = 0; g < 2; ++g) {
    float lrow[4];
#pragma unroll
    for (int r = 0; r < 4; ++r) lrow[r] = __shfl(l_l[g], quad * 4 + r, 64);
#pragma unroll
    for (int t = 0; t < 4; ++t)
#pragma unroll
      for (int r = 0; r < 4; ++r) {
        const int s = qb * 128 + g * 64 + wave * 16 + quad * 4 + r;
        const int d = h * 64 + t * 16 + lr;
        O[((size_t)(b * SS + s)) * DD + d] = f2b(accO[g][t][r] / lrow[r]);
      }
  }
}

// ---------------------------------------------------------------------------
extern "C" void kernel_launch(void* const* d_in, const int* in_sizes, int n_in,
                              void* d_out, int out_size, void* d_ws, size_t ws_size,
                              hipStream_t stream)
{
  const float* Qin = (const float*)d_in[0];
  const float* Kin = (const float*)d_in[1];
  const float* Vin = (const float*)d_in[2];
  const float* Wq  = (const float*)d_in[3];
  const float* bq  = (const float*)d_in[4];
  const float* Wk  = (const float*)d_in[5];
  const float* bk  = (const float*)d_in[6];
  const float* Wv  = (const float*)d_in[7];
  const float* bv  = (const float*)d_in[8];
  const float* Wo  = (const float*)d_in[9];
  const float* bo  = (const float*)d_in[10];
  float* out = (float*)d_out;

  const size_t TSZ = (size_t)MT * DD;   // 4M elements
  const size_t WSZ = (size_t)DD * DD;   // 1M elements
  dim3 blk(256);

  // d_out scratch for Wq/Wk/Wv bf16 (consumed by gemm_qkv; overwritten at end)
  u16* cWq = (u16*)d_out;
  u16* cWk = cWq + WSZ;
  u16* cWv = cWk + WSZ;

  u16* pQ   = (u16*)d_ws;
  u16* pK   = pQ  + TSZ;
  u16* pV   = pK  + TSZ;
  u16* wsVt = pV  + TSZ;
  u16* wsO  = wsVt + TSZ;

  if (ws_size >= (8*TSZ + WSZ) * sizeof(u16)) {
    u16* cQ  = wsO + TSZ;
    u16* cK  = cQ  + TSZ;
    u16* cV  = cK  + TSZ;
    u16* cWo = cV  + TSZ;
    cast_all<<<dim3(TSZ/8/256, 7), blk, 0, stream>>>(
        Qin, Kin, Vin, Wq, Wk, Wv, Wo, cQ, cK, cV, cWq, cWk, cWv, cWo);
    gemm_qkv_async<<<dim3(24, MT/128), blk, 0, stream>>>(
        cQ, cK, cV, cWq, cWk, cWv, bq, bk, bv, pQ, pK, pV);
    transpose_v<<<dim3(SS/64, HH, BB), blk, 0, stream>>>(pV, wsVt);
    attn<<<dim3(SS/128, HH, BB), blk, 0, stream>>>(pQ, pK, wsVt, wsO);
    gemm_out_async<<<dim3(DD/128, MT/128), blk, 0, stream>>>(wsO, cWo, bo, out);
  } else {
    cast_w3<<<dim3(WSZ/8/256, 3), blk, 0, stream>>>(Wq, Wk, Wv, cWq);
    gemm_qkv_fb<<<dim3(24, MT/128), blk, 0, stream>>>(
        Qin, Kin, Vin, cWq, cWk, cWv, bq, bk, bv, pQ, pK, pV);
    transpose_v<<<dim3(SS/64, HH, BB), blk, 0, stream>>>(pV, wsVt);
    attn<<<dim3(SS/128, HH, BB), blk, 0, stream>>>(pQ, pK, wsVt, wsO);
    gemm_out_fb<<<dim3(DD/128, MT/128), blk, 0, stream>>>(wsO, Wo, bo, out);
  }
}